// Round 2
// baseline (353.735 us; speedup 1.0000x reference)
//
#include <hip/hip_runtime.h>
#include <hip/hip_bf16.h>

#define BB 2
#define HH 16
#define SS 2048
#define DD 128
#define QBLK 64
#define KVBLK 64
#define VTP 72   // KVBLK + 8 pad: 144B row pitch, conflict-free for b128 writes / b64 reads

typedef __bf16 bf16x8 __attribute__((ext_vector_type(8)));
typedef __bf16 bf16x4 __attribute__((ext_vector_type(4)));
typedef float  f32x4  __attribute__((ext_vector_type(4)));

__global__ __launch_bounds__(256)
void attn_fwd(const float* __restrict__ Q, const float* __restrict__ K,
              const float* __restrict__ V, const int* __restrict__ M,
              float* __restrict__ O)
{
    __shared__ __bf16 Klds[KVBLK * DD];   // XOR-swizzled 16B units within each row
    __shared__ __bf16 Vt[DD * VTP];       // V transposed: Vt[d][k]

    const int tid  = threadIdx.x;
    const int w    = tid >> 6;
    const int lane = tid & 63;
    const int lr   = lane & 15;
    const int lg   = lane >> 4;

    // bijective XCD-chunked swizzle: nwg = 1024, 8 XCDs, 128 blocks/XCD,
    // consecutive swz (same bh) land on the same XCD -> K/V L2 reuse.
    const int bid = blockIdx.x;
    const int swz = (bid & 7) * 128 + (bid >> 3);
    const int qb  = swz & 31;        // SS/QBLK - 1
    const int bh  = swz >> 5;
    const int b   = bh >> 4;
    const int q0  = qb * QBLK + w * 16;

    const float scale = 0.08838834764831845f; // 1/sqrt(128)

    const float* Qb = Q + (size_t)bh * SS * DD;
    const float* Kb = K + (size_t)bh * SS * DD;
    const float* Vb = V + (size_t)bh * SS * DD;
    const int*   Mb = M + (size_t)b * SS * SS;
    float*       Ob = O + (size_t)bh * SS * DD;

    const int qrow = q0 + lr;   // this lane's q-row (swapped layout: q = lane&15)

    // ---- Q fragment (B-operand), loaded once: Q[qrow][d0*32 + lg*8 + 0..7] ----
    bf16x8 qf[4];
    {
        const float* qr = Qb + (size_t)qrow * DD;
        #pragma unroll
        for (int d0 = 0; d0 < 4; ++d0) {
            float4 f0 = *(const float4*)(qr + d0 * 32 + lg * 8);
            float4 f1 = *(const float4*)(qr + d0 * 32 + lg * 8 + 4);
            bf16x8 a;
            a[0]=(__bf16)f0.x; a[1]=(__bf16)f0.y; a[2]=(__bf16)f0.z; a[3]=(__bf16)f0.w;
            a[4]=(__bf16)f1.x; a[5]=(__bf16)f1.y; a[6]=(__bf16)f1.z; a[7]=(__bf16)f1.w;
            qf[d0] = a;
        }
    }

    f32x4 o[8];
    #pragma unroll
    for (int i = 0; i < 8; ++i) o[i] = (f32x4)0.0f;
    float m_i = -1e30f, l_i = 0.0f;

    const int* mrow = Mb + (size_t)qrow * SS;

    for (int kv0 = 0; kv0 < SS; kv0 += KVBLK) {
        __syncthreads();   // previous tile fully consumed by all waves

        // ---- stage K: [64][128] fp32 -> bf16, fully-coalesced reads, swizzled 8B writes ----
        {
            const int r0 = tid >> 5;    // 0..7
            const int c4 = tid & 31;    // float4 column
            #pragma unroll
            for (int it = 0; it < 8; ++it) {
                const int r = it * 8 + r0;
                float4 f = *(const float4*)(Kb + (size_t)(kv0 + r) * DD + c4 * 4);
                bf16x4 h;
                h[0]=(__bf16)f.x; h[1]=(__bf16)f.y; h[2]=(__bf16)f.z; h[3]=(__bf16)f.w;
                const int u = (c4 >> 1) ^ (r & 7);
                *(bf16x4*)&Klds[r * DD + u * 8 + (c4 & 1) * 4] = h;
            }
        }
        // ---- stage V transposed: Vt[d][k] (lane-coalesced scalar reads, b128 writes) ----
        {
            const int d  = tid & 127;
            const int kh = tid >> 7;    // 0..1 -> k in [kh*32, kh*32+32)
            const float* src = Vb + (size_t)(kv0 + kh * 32) * DD + d;
            #pragma unroll
            for (int j = 0; j < 4; ++j) {
                bf16x8 t;
                #pragma unroll
                for (int e = 0; e < 8; ++e)
                    t[e] = (__bf16)src[(size_t)(j * 8 + e) * DD];
                *(bf16x8*)&Vt[d * VTP + kh * 32 + j * 8] = t;
            }
        }
        __syncthreads();

        // ---- QK^T swapped: S^T[k][q] = mfma(K_frag, Q_frag) ----
        f32x4 s[4];
        #pragma unroll
        for (int kt = 0; kt < 4; ++kt) {
            s[kt] = (f32x4)0.0f;
            const int krow = kt * 16 + lr;
            const int sw   = krow & 7;
            #pragma unroll
            for (int d0 = 0; d0 < 4; ++d0) {
                bf16x8 kf = *(const bf16x8*)&Klds[krow * DD + ((d0 * 4 + lg) ^ sw) * 8];
                s[kt] = __builtin_amdgcn_mfma_f32_16x16x32_bf16(kf, qf[d0], s[kt], 0, 0, 0);
            }
        }

        // ---- mask + scale (int4 mask loads), online softmax (lane-local rows) ----
        float mx = -1e30f;
        #pragma unroll
        for (int kt = 0; kt < 4; ++kt) {
            int4 mm = *(const int4*)(mrow + kv0 + kt * 16 + lg * 4);
            s[kt][0] = s[kt][0] * scale - 1e9f * (float)mm.x;
            s[kt][1] = s[kt][1] * scale - 1e9f * (float)mm.y;
            s[kt][2] = s[kt][2] * scale - 1e9f * (float)mm.z;
            s[kt][3] = s[kt][3] * scale - 1e9f * (float)mm.w;
            mx = fmaxf(mx, fmaxf(fmaxf(s[kt][0], s[kt][1]), fmaxf(s[kt][2], s[kt][3])));
        }
        mx = fmaxf(mx, __shfl_xor(mx, 16));
        mx = fmaxf(mx, __shfl_xor(mx, 32));

        const float newm  = fmaxf(m_i, mx);
        const float alpha = __expf(m_i - newm);
        m_i = newm;

        float rs = 0.0f;
        #pragma unroll
        for (int kt = 0; kt < 4; ++kt) {
            #pragma unroll
            for (int r = 0; r < 4; ++r) {
                const float p = __expf(s[kt][r] - newm);
                s[kt][r] = p;
                rs += p;
            }
        }
        rs += __shfl_xor(rs, 16);
        rs += __shfl_xor(rs, 32);
        l_i = l_i * alpha + rs;

        #pragma unroll
        for (int dt = 0; dt < 8; ++dt) {
            o[dt][0] *= alpha; o[dt][1] *= alpha;
            o[dt][2] *= alpha; o[dt][3] *= alpha;
        }

        // ---- PV: O^T[d][q] += mfma(V^T_frag, P^T_frag) with matching k-slot perm ----
        #pragma unroll
        for (int ch = 0; ch < 2; ++ch) {
            bf16x8 pb;
            pb[0]=(__bf16)s[2*ch][0];   pb[1]=(__bf16)s[2*ch][1];
            pb[2]=(__bf16)s[2*ch][2];   pb[3]=(__bf16)s[2*ch][3];
            pb[4]=(__bf16)s[2*ch+1][0]; pb[5]=(__bf16)s[2*ch+1][1];
            pb[6]=(__bf16)s[2*ch+1][2]; pb[7]=(__bf16)s[2*ch+1][3];
            #pragma unroll
            for (int dt = 0; dt < 8; ++dt) {
                const __bf16* vp = &Vt[(dt * 16 + lr) * VTP + ch * 32 + lg * 4];
                bf16x4 v0 = *(const bf16x4*)vp;
                bf16x4 v1 = *(const bf16x4*)(vp + 16);
                bf16x8 va;
                va[0]=v0[0]; va[1]=v0[1]; va[2]=v0[2]; va[3]=v0[3];
                va[4]=v1[0]; va[5]=v1[1]; va[6]=v1[2]; va[7]=v1[3];
                o[dt] = __builtin_amdgcn_mfma_f32_16x16x32_bf16(va, pb, o[dt], 0, 0, 0);
            }
        }
    }

    // ---- epilogue: lane owns q=qrow, d = dt*16 + lg*4 + r -> float4 stores ----
    const float inv = 1.0f / l_i;
    float* orow = Ob + (size_t)qrow * DD;
    #pragma unroll
    for (int dt = 0; dt < 8; ++dt) {
        float4 st;
        st.x = o[dt][0] * inv; st.y = o[dt][1] * inv;
        st.z = o[dt][2] * inv; st.w = o[dt][3] * inv;
        *(float4*)&orow[dt * 16 + lg * 4] = st;
    }
}

extern "C" void kernel_launch(void* const* d_in, const int* in_sizes, int n_in,
                              void* d_out, int out_size, void* d_ws, size_t ws_size,
                              hipStream_t stream) {
    const float* Q = (const float*)d_in[0];
    const float* K = (const float*)d_in[1];
    const float* V = (const float*)d_in[2];
    const int*   M = (const int*)d_in[4];
    float*       O = (float*)d_out;

    dim3 grid(BB * HH * (SS / QBLK));   // 1024, swizzled in-kernel
    dim3 block(256);
    attn_fwd<<<grid, block, 0, stream>>>(Q, K, V, M, O);
}

// Round 3
// 192.432 us; speedup vs baseline: 1.8382x; 1.8382x over previous
//
#include <hip/hip_runtime.h>
#include <hip/hip_bf16.h>

#define BB 2
#define HH 16
#define SS 2048
#define DD 128
#define QBLK 64
#define KVBLK 64
#define NT (SS / KVBLK)
#define VTP 72   // KVBLK + 8 pad (144B pitch)

typedef __bf16 bf16x8 __attribute__((ext_vector_type(8)));
typedef __bf16 bf16x4 __attribute__((ext_vector_type(4)));
typedef float  f32x4  __attribute__((ext_vector_type(4)));

// ---- staging: issue global loads (no wait) ----
#define ISSUE_KV(kv0)                                                          \
    do {                                                                       \
        _Pragma("unroll")                                                      \
        for (int it = 0; it < 8; ++it)                                         \
            kst[it] = *(const float4*)(Kb + (size_t)((kv0) + it * 8 + r0) * DD + c4 * 4); \
        const float* vsrc = Vb + (size_t)((kv0) + vkh * 32) * DD + vd;         \
        _Pragma("unroll")                                                      \
        for (int j = 0; j < 32; ++j)                                           \
            vst[j] = vsrc[(size_t)j * DD];                                     \
    } while (0)

#define ISSUE_M(MST, kv0)                                                      \
    do {                                                                       \
        _Pragma("unroll")                                                      \
        for (int kt = 0; kt < 4; ++kt)                                         \
            MST[kt] = *(const int4*)(mrow + (kv0) + kt * 16 + lg * 4);         \
    } while (0)

// ---- convert staged regs -> LDS (compiler inserts the vmcnt waits) ----
#define WRITE_LDS(BUF)                                                         \
    do {                                                                       \
        _Pragma("unroll")                                                      \
        for (int it = 0; it < 8; ++it) {                                       \
            const int r = it * 8 + r0;                                         \
            float4 f = kst[it];                                                \
            bf16x4 h;                                                          \
            h[0] = (__bf16)f.x; h[1] = (__bf16)f.y;                            \
            h[2] = (__bf16)f.z; h[3] = (__bf16)f.w;                            \
            const int u = (c4 >> 1) ^ (r & 7);                                 \
            *(bf16x4*)&Klds[BUF][r * DD + u * 8 + (c4 & 1) * 4] = h;           \
        }                                                                      \
        _Pragma("unroll")                                                      \
        for (int j4 = 0; j4 < 4; ++j4) {                                       \
            bf16x8 tv;                                                         \
            _Pragma("unroll")                                                  \
            for (int e = 0; e < 8; ++e) tv[e] = (__bf16)vst[j4 * 8 + e];       \
            *(bf16x8*)&Vt[BUF][vd * VTP + vkh * 32 + j4 * 8] = tv;             \
        }                                                                      \
    } while (0)

// ---- one KV-tile of compute: QK^T (swapped), online softmax, PV ----
#define COMPUTE_TILE(BUF, MST)                                                 \
    do {                                                                       \
        const __bf16* KL = Klds[BUF];                                          \
        const __bf16* VL = Vt[BUF];                                            \
        f32x4 s[4];                                                            \
        _Pragma("unroll")                                                      \
        for (int kt = 0; kt < 4; ++kt) {                                       \
            s[kt] = (f32x4)0.0f;                                               \
            const int krow = kt * 16 + lr;                                     \
            const int sw   = krow & 7;                                         \
            _Pragma("unroll")                                                  \
            for (int d0 = 0; d0 < 4; ++d0) {                                   \
                bf16x8 kf = *(const bf16x8*)&KL[krow * DD + ((d0 * 4 + lg) ^ sw) * 8]; \
                s[kt] = __builtin_amdgcn_mfma_f32_16x16x32_bf16(kf, qf[d0], s[kt], 0, 0, 0); \
            }                                                                  \
        }                                                                      \
        float mx = -1e30f;                                                     \
        _Pragma("unroll")                                                      \
        for (int kt = 0; kt < 4; ++kt) {                                       \
            int4 mm = MST[kt];                                                 \
            s[kt][0] = s[kt][0] * scale2 + mcoef * (float)mm.x;                \
            s[kt][1] = s[kt][1] * scale2 + mcoef * (float)mm.y;                \
            s[kt][2] = s[kt][2] * scale2 + mcoef * (float)mm.z;                \
            s[kt][3] = s[kt][3] * scale2 + mcoef * (float)mm.w;                \
            mx = fmaxf(mx, fmaxf(fmaxf(s[kt][0], s[kt][1]),                    \
                                 fmaxf(s[kt][2], s[kt][3])));                  \
        }                                                                      \
        mx = fmaxf(mx, __shfl_xor(mx, 16));                                    \
        mx = fmaxf(mx, __shfl_xor(mx, 32));                                    \
        if (__any(mx > m2 + 11.5415603f)) {   /* defer-max: rarely taken */    \
            const float newm  = fmaxf(m2, mx);                                 \
            const float alpha = exp2f(m2 - newm);                              \
            m2 = newm;                                                         \
            l_i *= alpha;                                                      \
            _Pragma("unroll")                                                  \
            for (int dt = 0; dt < 8; ++dt) {                                   \
                o[dt][0] *= alpha; o[dt][1] *= alpha;                          \
                o[dt][2] *= alpha; o[dt][3] *= alpha;                          \
            }                                                                  \
        }                                                                      \
        float rs = 0.0f;                                                       \
        _Pragma("unroll")                                                      \
        for (int kt = 0; kt < 4; ++kt) {                                       \
            _Pragma("unroll")                                                  \
            for (int r = 0; r < 4; ++r) {                                      \
                const float p = exp2f(s[kt][r] - m2);                          \
                s[kt][r] = p;                                                  \
                rs += p;                                                       \
            }                                                                  \
        }                                                                      \
        rs += __shfl_xor(rs, 16);                                              \
        rs += __shfl_xor(rs, 32);                                              \
        l_i += rs;                                                             \
        _Pragma("unroll")                                                      \
        for (int ch = 0; ch < 2; ++ch) {                                       \
            bf16x8 pb;                                                         \
            pb[0] = (__bf16)s[2*ch][0];   pb[1] = (__bf16)s[2*ch][1];          \
            pb[2] = (__bf16)s[2*ch][2];   pb[3] = (__bf16)s[2*ch][3];          \
            pb[4] = (__bf16)s[2*ch+1][0]; pb[5] = (__bf16)s[2*ch+1][1];        \
            pb[6] = (__bf16)s[2*ch+1][2]; pb[7] = (__bf16)s[2*ch+1][3];        \
            _Pragma("unroll")                                                  \
            for (int dt = 0; dt < 8; ++dt) {                                   \
                const __bf16* vp = &VL[(dt * 16 + lr) * VTP + ch * 32 + lg * 4]; \
                bf16x4 v0 = *(const bf16x4*)vp;                                \
                bf16x4 v1 = *(const bf16x4*)(vp + 16);                         \
                bf16x8 va;                                                     \
                va[0] = v0[0]; va[1] = v0[1]; va[2] = v0[2]; va[3] = v0[3];    \
                va[4] = v1[0]; va[5] = v1[1]; va[6] = v1[2]; va[7] = v1[3];    \
                o[dt] = __builtin_amdgcn_mfma_f32_16x16x32_bf16(va, pb, o[dt], 0, 0, 0); \
            }                                                                  \
        }                                                                      \
    } while (0)

#define LGKM0_BARRIER()                                                        \
    do {                                                                       \
        asm volatile("s_waitcnt lgkmcnt(0)" ::: "memory");                     \
        __builtin_amdgcn_s_barrier();                                          \
    } while (0)

__global__ __launch_bounds__(256, 2)
void attn_fwd(const float* __restrict__ Q, const float* __restrict__ K,
              const float* __restrict__ V, const int* __restrict__ M,
              float* __restrict__ O)
{
    __shared__ __bf16 Klds[2][KVBLK * DD];
    __shared__ __bf16 Vt[2][DD * VTP];

    const int tid  = threadIdx.x;
    const int lane = tid & 63;
    const int lr   = lane & 15;
    const int lg   = lane >> 4;
    const int w    = tid >> 6;

    // bijective XCD-chunked swizzle (nwg=1024, 8 XCDs, 128/XCD)
    const int bid = blockIdx.x;
    const int swz = (bid & 7) * 128 + (bid >> 3);
    const int qb  = swz & 31;
    const int bh  = swz >> 5;
    const int b   = bh >> 4;
    const int q0  = qb * QBLK + w * 16;

    const float scale2 = 0.08838834764831845f * 1.4426950408889634f; // /sqrt(d) * log2e
    const float mcoef  = -1.4426950408889634e9f;                     // -1e9 * log2e

    const float* Qb = Q + (size_t)bh * SS * DD;
    const float* Kb = K + (size_t)bh * SS * DD;
    const float* Vb = V + (size_t)bh * SS * DD;
    const int*   Mb = M + (size_t)b * SS * SS;
    float*       Ob = O + (size_t)bh * SS * DD;

    const int  qrow = q0 + lr;
    const int* mrow = Mb + (size_t)qrow * SS;

    // staging thread roles
    const int r0  = tid >> 5;    // K: row 0..7
    const int c4  = tid & 31;    // K: float4 col
    const int vd  = tid & 127;   // V: d
    const int vkh = tid >> 7;    // V: k-half

    // ---- Q fragment (B-operand), loaded once ----
    bf16x8 qf[4];
    {
        const float* qr = Qb + (size_t)qrow * DD;
        #pragma unroll
        for (int d0 = 0; d0 < 4; ++d0) {
            float4 f0 = *(const float4*)(qr + d0 * 32 + lg * 8);
            float4 f1 = *(const float4*)(qr + d0 * 32 + lg * 8 + 4);
            bf16x8 a;
            a[0]=(__bf16)f0.x; a[1]=(__bf16)f0.y; a[2]=(__bf16)f0.z; a[3]=(__bf16)f0.w;
            a[4]=(__bf16)f1.x; a[5]=(__bf16)f1.y; a[6]=(__bf16)f1.z; a[7]=(__bf16)f1.w;
            qf[d0] = a;
        }
    }

    f32x4 o[8];
    #pragma unroll
    for (int i = 0; i < 8; ++i) o[i] = (f32x4)0.0f;
    float m2 = -1e30f, l_i = 0.0f;

    // staged-load registers
    float4 kst[8];
    float  vst[32];
    int4   mstA[4], mstB[4];

    // ---- pipeline prologue ----
    ISSUE_KV(0);
    ISSUE_M(mstA, 0);
    WRITE_LDS(0);
    ISSUE_KV(KVBLK);
    ISSUE_M(mstB, KVBLK);
    LGKM0_BARRIER();

    // ---- main loop: 1 raw barrier per tile, loads in flight across it ----
    #pragma unroll 1
    for (int t = 0; t < NT; t += 2) {
        COMPUTE_TILE(0, mstA);
        WRITE_LDS(1);                               // tile t+1 (waits its vmcnt)
        if (t + 2 < NT) {
            ISSUE_KV((t + 2) * KVBLK);
            ISSUE_M(mstA, (t + 2) * KVBLK);
        }
        LGKM0_BARRIER();

        COMPUTE_TILE(1, mstB);
        if (t + 2 < NT) {
            WRITE_LDS(0);                           // tile t+2
            ISSUE_KV((t + 3) * KVBLK);
            ISSUE_M(mstB, (t + 3) * KVBLK);
        }
        LGKM0_BARRIER();
    }

    // ---- epilogue ----
    const float inv = 1.0f / l_i;
    float* orow = Ob + (size_t)qrow * DD;
    #pragma unroll
    for (int dt = 0; dt < 8; ++dt) {
        float4 st;
        st.x = o[dt][0] * inv; st.y = o[dt][1] * inv;
        st.z = o[dt][2] * inv; st.w = o[dt][3] * inv;
        *(float4*)&orow[dt * 16 + lg * 4] = st;
    }
}

extern "C" void kernel_launch(void* const* d_in, const int* in_sizes, int n_in,
                              void* d_out, int out_size, void* d_ws, size_t ws_size,
                              hipStream_t stream) {
    const float* Q = (const float*)d_in[0];
    const float* K = (const float*)d_in[1];
    const float* V = (const float*)d_in[2];
    const int*   M = (const int*)d_in[4];
    float*       O = (float*)d_out;

    dim3 grid(BB * HH * (SS / QBLK));   // 1024 blocks, swizzled in-kernel
    dim3 block(256);
    attn_fwd<<<grid, block, 0, stream>>>(Q, K, V, M, O);
}

// Round 4
// 163.397 us; speedup vs baseline: 2.1649x; 1.1777x over previous
//
#include <hip/hip_runtime.h>
#include <hip/hip_bf16.h>

#define BB 2
#define HH 16
#define SS 2048
#define DD 128
#define QBLK 64
#define KVBLK 64
#define NT (SS / KVBLK)
#define VTP 68   // 136B pitch = 17 x 8B units: bank-shift 2/row -> conflict-free b64 reads

typedef __bf16 bf16x8 __attribute__((ext_vector_type(8)));
typedef __bf16 bf16x4 __attribute__((ext_vector_type(4)));
typedef float  f32x4  __attribute__((ext_vector_type(4)));

// ================= pre-pass 1: K fp32 -> bf16 (row-major) =================
__global__ __launch_bounds__(256)
void kconv(const float* __restrict__ K, __bf16* __restrict__ Kd)
{
    const size_t nchunk = (size_t)BB * HH * SS * DD / 8;   // 1,048,576
    size_t c = (size_t)blockIdx.x * 256 + threadIdx.x;
    for (; c < nchunk; c += (size_t)2048 * 256) {
        const float* s = K + c * 8;
        float4 f0 = *(const float4*)(s);
        float4 f1 = *(const float4*)(s + 4);
        bf16x8 h;
        h[0]=(__bf16)f0.x; h[1]=(__bf16)f0.y; h[2]=(__bf16)f0.z; h[3]=(__bf16)f0.w;
        h[4]=(__bf16)f1.x; h[5]=(__bf16)f1.y; h[6]=(__bf16)f1.z; h[7]=(__bf16)f1.w;
        *(bf16x8*)(Kd + c * 8) = h;
    }
}

// ============ pre-pass 2: V fp32 [bh][s][d] -> bf16 V^T [bh][d][s] ============
__global__ __launch_bounds__(256)
void vtrans(const float* __restrict__ V, __bf16* __restrict__ Vt)
{
    __shared__ float T[64][65];
    const int bid = blockIdx.x;          // bh*64 + tile
    const int bh  = bid >> 6;
    const int t   = bid & 63;
    const int k0  = (t >> 1) * 64;
    const int d0  = (t & 1) * 64;

    const float* src = V + ((size_t)bh * SS + k0) * DD + d0;
    const int r = threadIdx.x >> 4;
    const int c = (threadIdx.x & 15) * 4;
    #pragma unroll
    for (int it = 0; it < 4; ++it) {
        float4 f = *(const float4*)(src + (size_t)(it * 16 + r) * DD + c);
        T[it*16 + r][c]     = f.x;
        T[it*16 + r][c + 1] = f.y;
        T[it*16 + r][c + 2] = f.z;
        T[it*16 + r][c + 3] = f.w;
    }
    __syncthreads();

    const int d  = threadIdx.x >> 2;
    const int kq = (threadIdx.x & 3) * 16;
    __bf16* dst = Vt + ((size_t)bh * DD + d0 + d) * SS + k0 + kq;
    bf16x8 a, b;
    #pragma unroll
    for (int j = 0; j < 8; ++j) a[j] = (__bf16)T[kq + j][d];
    #pragma unroll
    for (int j = 0; j < 8; ++j) b[j] = (__bf16)T[kq + 8 + j][d];
    *(bf16x8*)dst       = a;
    *(bf16x8*)(dst + 8) = b;
}

// ========================== main attention kernel ==========================
// staging: issue global bf16 loads (no wait)
#define ISSUE_KV(kv0)                                                          \
    do {                                                                       \
        _Pragma("unroll")                                                      \
        for (int it = 0; it < 4; ++it) {                                       \
            const int c = it * 256 + tid;                                      \
            kst[it] = *(const bf16x8*)(Kb2 + (size_t)((kv0) + (c >> 4)) * DD + (c & 15) * 8); \
        }                                                                      \
        _Pragma("unroll")                                                      \
        for (int it = 0; it < 4; ++it) {                                       \
            const int c = it * 256 + tid;                                      \
            vst[it] = *(const bf16x8*)(Vg2 + (size_t)(c >> 3) * SS + (kv0) + (c & 7) * 8); \
        }                                                                      \
    } while (0)

#define ISSUE_M(MST, kv0)                                                      \
    do {                                                                       \
        _Pragma("unroll")                                                      \
        for (int kt = 0; kt < 4; ++kt)                                         \
            MST[kt] = *(const int4*)(mrow + (kv0) + kt * 16 + lg * 4);         \
    } while (0)

// staged regs -> LDS (compiler inserts the vmcnt waits)
#define WRITE_LDS(BUF)                                                         \
    do {                                                                       \
        _Pragma("unroll")                                                      \
        for (int it = 0; it < 4; ++it) {                                       \
            const int c = it * 256 + tid;                                      \
            const int r = c >> 4, u = c & 15;                                  \
            *(bf16x8*)&Klds[BUF][r * DD + (u ^ (r & 7)) * 8] = kst[it];        \
        }                                                                      \
        _Pragma("unroll")                                                      \
        for (int it = 0; it < 4; ++it) {                                       \
            const int c = it * 256 + tid;                                      \
            const int d = c >> 3, ku = c & 7;                                  \
            __bf16* p = &Vt[BUF][d * VTP + ku * 8];                            \
            bf16x8 tv = vst[it];                                               \
            bf16x4 lo, hi;                                                     \
            lo[0]=tv[0]; lo[1]=tv[1]; lo[2]=tv[2]; lo[3]=tv[3];                \
            hi[0]=tv[4]; hi[1]=tv[5]; hi[2]=tv[6]; hi[3]=tv[7];                \
            *(bf16x4*)p       = lo;                                            \
            *(bf16x4*)(p + 4) = hi;                                            \
        }                                                                      \
    } while (0)

#define COMPUTE_TILE(BUF, MST)                                                 \
    do {                                                                       \
        const __bf16* KL = Klds[BUF];                                          \
        const __bf16* VL = Vt[BUF];                                            \
        f32x4 s[4];                                                            \
        _Pragma("unroll")                                                      \
        for (int kt = 0; kt < 4; ++kt) {                                       \
            s[kt] = (f32x4)0.0f;                                               \
            const int krow = kt * 16 + lr;                                     \
            const int sw   = krow & 7;                                         \
            _Pragma("unroll")                                                  \
            for (int d0 = 0; d0 < 4; ++d0) {                                   \
                bf16x8 kf = *(const bf16x8*)&KL[krow * DD + ((d0 * 4 + lg) ^ sw) * 8]; \
                s[kt] = __builtin_amdgcn_mfma_f32_16x16x32_bf16(kf, qf[d0], s[kt], 0, 0, 0); \
            }                                                                  \
        }                                                                      \
        float mx = -1e30f;                                                     \
        _Pragma("unroll")                                                      \
        for (int kt = 0; kt < 4; ++kt) {                                       \
            int4 mm = MST[kt];                                                 \
            s[kt][0] = s[kt][0] * scale2 + mcoef * (float)mm.x;                \
            s[kt][1] = s[kt][1] * scale2 + mcoef * (float)mm.y;                \
            s[kt][2] = s[kt][2] * scale2 + mcoef * (float)mm.z;                \
            s[kt][3] = s[kt][3] * scale2 + mcoef * (float)mm.w;                \
            mx = fmaxf(mx, fmaxf(fmaxf(s[kt][0], s[kt][1]),                    \
                                 fmaxf(s[kt][2], s[kt][3])));                  \
        }                                                                      \
        mx = fmaxf(mx, __shfl_xor(mx, 16));                                    \
        mx = fmaxf(mx, __shfl_xor(mx, 32));                                    \
        if (__any(mx > m2 + 11.5415603f)) {   /* defer-max: rarely taken */    \
            const float newm  = fmaxf(m2, mx);                                 \
            const float alpha = exp2f(m2 - newm);                              \
            m2 = newm;                                                         \
            l_i *= alpha;                                                      \
            _Pragma("unroll")                                                  \
            for (int dt = 0; dt < 8; ++dt) {                                   \
                o[dt][0] *= alpha; o[dt][1] *= alpha;                          \
                o[dt][2] *= alpha; o[dt][3] *= alpha;                          \
            }                                                                  \
        }                                                                      \
        float rs = 0.0f;                                                       \
        _Pragma("unroll")                                                      \
        for (int kt = 0; kt < 4; ++kt) {                                       \
            _Pragma("unroll")                                                  \
            for (int r = 0; r < 4; ++r) {                                      \
                const float p = exp2f(s[kt][r] - m2);                          \
                s[kt][r] = p;                                                  \
                rs += p;                                                       \
            }                                                                  \
        }                                                                      \
        rs += __shfl_xor(rs, 16);                                              \
        rs += __shfl_xor(rs, 32);                                              \
        l_i += rs;                                                             \
        _Pragma("unroll")                                                      \
        for (int ch = 0; ch < 2; ++ch) {                                       \
            bf16x8 pb;                                                         \
            pb[0] = (__bf16)s[2*ch][0];   pb[1] = (__bf16)s[2*ch][1];          \
            pb[2] = (__bf16)s[2*ch][2];   pb[3] = (__bf16)s[2*ch][3];          \
            pb[4] = (__bf16)s[2*ch+1][0]; pb[5] = (__bf16)s[2*ch+1][1];        \
            pb[6] = (__bf16)s[2*ch+1][2]; pb[7] = (__bf16)s[2*ch+1][3];        \
            _Pragma("unroll")                                                  \
            for (int dt = 0; dt < 8; ++dt) {                                   \
                const __bf16* vp = &VL[(dt * 16 + lr) * VTP + ch * 32 + lg * 4]; \
                bf16x4 v0 = *(const bf16x4*)vp;                                \
                bf16x4 v1 = *(const bf16x4*)(vp + 16);                         \
                bf16x8 va;                                                     \
                va[0] = v0[0]; va[1] = v0[1]; va[2] = v0[2]; va[3] = v0[3];    \
                va[4] = v1[0]; va[5] = v1[1]; va[6] = v1[2]; va[7] = v1[3];    \
                o[dt] = __builtin_amdgcn_mfma_f32_16x16x32_bf16(va, pb, o[dt], 0, 0, 0); \
            }                                                                  \
        }                                                                      \
    } while (0)

#define LGKM0_BARRIER()                                                        \
    do {                                                                       \
        asm volatile("s_waitcnt lgkmcnt(0)" ::: "memory");                     \
        __builtin_amdgcn_s_barrier();                                          \
    } while (0)

__global__ __launch_bounds__(256, 2)
void attn_fwd(const float* __restrict__ Q, const __bf16* __restrict__ Kc,
              const __bf16* __restrict__ Vc, const int* __restrict__ M,
              float* __restrict__ O)
{
    __shared__ __bf16 Klds[2][KVBLK * DD];
    __shared__ __bf16 Vt[2][DD * VTP];

    const int tid  = threadIdx.x;
    const int lane = tid & 63;
    const int lr   = lane & 15;
    const int lg   = lane >> 4;
    const int w    = tid >> 6;

    // bijective XCD-chunked swizzle (nwg=1024, 8 XCDs, 128/XCD)
    const int bid = blockIdx.x;
    const int swz = (bid & 7) * 128 + (bid >> 3);
    const int qb  = swz & 31;
    const int bh  = swz >> 5;
    const int b   = bh >> 4;
    const int q0  = qb * QBLK + w * 16;

    const float scale2 = 0.08838834764831845f * 1.4426950408889634f; // /sqrt(d)*log2e
    const float mcoef  = -1.4426950408889634e9f;                     // -1e9*log2e

    const float*  Qb  = Q  + (size_t)bh * SS * DD;
    const __bf16* Kb2 = Kc + (size_t)bh * SS * DD;
    const __bf16* Vg2 = Vc + (size_t)bh * DD * SS;   // V^T: [d][s]
    const int*    Mb  = M  + (size_t)b * SS * SS;
    float*        Ob  = O  + (size_t)bh * SS * DD;

    const int  qrow = q0 + lr;
    const int* mrow = Mb + (size_t)qrow * SS;

    // ---- Q fragment (B-operand), loaded once ----
    bf16x8 qf[4];
    {
        const float* qr = Qb + (size_t)qrow * DD;
        #pragma unroll
        for (int d0 = 0; d0 < 4; ++d0) {
            float4 f0 = *(const float4*)(qr + d0 * 32 + lg * 8);
            float4 f1 = *(const float4*)(qr + d0 * 32 + lg * 8 + 4);
            bf16x8 a;
            a[0]=(__bf16)f0.x; a[1]=(__bf16)f0.y; a[2]=(__bf16)f0.z; a[3]=(__bf16)f0.w;
            a[4]=(__bf16)f1.x; a[5]=(__bf16)f1.y; a[6]=(__bf16)f1.z; a[7]=(__bf16)f1.w;
            qf[d0] = a;
        }
    }

    f32x4 o[8];
    #pragma unroll
    for (int i = 0; i < 8; ++i) o[i] = (f32x4)0.0f;
    float m2 = -1e30f, l_i = 0.0f;

    bf16x8 kst[4], vst[4];
    int4   mstA[4], mstB[4];

    // ---- pipeline prologue ----
    ISSUE_KV(0);
    ISSUE_M(mstA, 0);
    WRITE_LDS(0);
    ISSUE_KV(KVBLK);
    ISSUE_M(mstB, KVBLK);
    LGKM0_BARRIER();

    // ---- main loop: 1 raw barrier per tile, loads in flight across it ----
    #pragma unroll 1
    for (int t = 0; t < NT; t += 2) {
        COMPUTE_TILE(0, mstA);
        WRITE_LDS(1);
        if (t + 2 < NT) {
            ISSUE_KV((t + 2) * KVBLK);
            ISSUE_M(mstA, (t + 2) * KVBLK);
        }
        LGKM0_BARRIER();

        COMPUTE_TILE(1, mstB);
        if (t + 2 < NT) {
            WRITE_LDS(0);
            ISSUE_KV((t + 3) * KVBLK);
            ISSUE_M(mstB, (t + 3) * KVBLK);
        }
        LGKM0_BARRIER();
    }

    // ---- epilogue ----
    const float inv = 1.0f / l_i;
    float* orow = Ob + (size_t)qrow * DD;
    #pragma unroll
    for (int dt = 0; dt < 8; ++dt) {
        float4 st;
        st.x = o[dt][0] * inv; st.y = o[dt][1] * inv;
        st.z = o[dt][2] * inv; st.w = o[dt][3] * inv;
        *(float4*)&orow[dt * 16 + lg * 4] = st;
    }
}

extern "C" void kernel_launch(void* const* d_in, const int* in_sizes, int n_in,
                              void* d_out, int out_size, void* d_ws, size_t ws_size,
                              hipStream_t stream) {
    const float* Q = (const float*)d_in[0];
    const float* K = (const float*)d_in[1];
    const float* V = (const float*)d_in[2];
    const int*   M = (const int*)d_in[4];
    float*       O = (float*)d_out;

    __bf16* Kc = (__bf16*)d_ws;                               // 16.78 MB
    __bf16* Vc = Kc + (size_t)BB * HH * SS * DD;              // 16.78 MB

    kconv <<<2048, 256, 0, stream>>>(K, Kc);
    vtrans<<<BB * HH * 64, 256, 0, stream>>>(V, Vc);

    dim3 grid(BB * HH * (SS / QBLK));   // 1024 blocks, swizzled in-kernel
    attn_fwd<<<grid, 256, 0, stream>>>(Q, Kc, Vc, M, O);
}

// Round 5
// 146.701 us; speedup vs baseline: 2.4113x; 1.1138x over previous
//
#include <hip/hip_runtime.h>
#include <hip/hip_bf16.h>

#define BB 2
#define HH 16
#define SS 2048
#define DD 128
#define QBLK 128
#define KVBLK 64
#define NT (SS / KVBLK)
#define TILE_ELEMS (KVBLK * DD)   // 8192 bf16 = 16 KB per K or V tile

typedef __bf16 bf16x8 __attribute__((ext_vector_type(8)));
typedef float  f32x4  __attribute__((ext_vector_type(4)));

// ============ pre-pass 1: K fp32 -> bf16 LDS-image (XOR-swizzled 16B units) ============
// image[g] (16B unit): tr = g>>4 (global row), u' = g&15 storage unit;
// content = K[tr][ (u' ^ (tr&7))*8 .. +8 ]
__global__ __launch_bounds__(256)
void kimg_prep(const float* __restrict__ K, __bf16* __restrict__ Kd)
{
    #pragma unroll
    for (int i = 0; i < 4; ++i) {
        const int g  = blockIdx.x * 1024 + i * 256 + threadIdx.x;
        const int tr = g >> 4;
        const int u  = (g & 15) ^ (tr & 7);
        const float* src = K + (size_t)tr * DD + u * 8;
        float4 f0 = *(const float4*)src;
        float4 f1 = *(const float4*)(src + 4);
        bf16x8 h;
        h[0]=(__bf16)f0.x; h[1]=(__bf16)f0.y; h[2]=(__bf16)f0.z; h[3]=(__bf16)f0.w;
        h[4]=(__bf16)f1.x; h[5]=(__bf16)f1.y; h[6]=(__bf16)f1.z; h[7]=(__bf16)f1.w;
        *(bf16x8*)(Kd + (size_t)g * 8) = h;
    }
}

// ===== pre-pass 2: V fp32 [s][d] -> bf16 V^T LDS-image (k-slot permuted + XOR) =====
// per tile (bt = bh*32+t): image unit iu: d = iu>>3, stored-unit us = iu&7,
// semantic unit pu = us ^ (d&7); element j of unit: position p = pu*8+j,
// semantic k = (p>>5)*32 + ((p>>2)&1)*16 + ((p>>3)&3)*4 + (p&3)
__global__ __launch_bounds__(256)
void vimg_prep(const float* __restrict__ V, __bf16* __restrict__ Vd)
{
    __shared__ float T[KVBLK][DD + 4];
    const int bt = blockIdx.x;                       // bh*32 + tile
    const float* src = V + (size_t)bt * KVBLK * DD;
    #pragma unroll
    for (int i = 0; i < 8; ++i) {
        const int idx = i * 256 + threadIdx.x;       // 0..2047
        const int r = idx >> 5, c4 = idx & 31;
        float4 f = *(const float4*)(src + (size_t)r * DD + c4 * 4);
        T[r][c4 * 4 + 0] = f.x; T[r][c4 * 4 + 1] = f.y;
        T[r][c4 * 4 + 2] = f.z; T[r][c4 * 4 + 3] = f.w;
    }
    __syncthreads();
    #pragma unroll
    for (int i = 0; i < 4; ++i) {
        const int iu = i * 256 + threadIdx.x;        // 0..1023
        const int d  = iu >> 3;
        const int pu = (iu & 7) ^ (d & 7);
        bf16x8 h;
        #pragma unroll
        for (int j = 0; j < 8; ++j) {
            const int p = pu * 8 + j;
            const int k = (p >> 5) * 32 + ((p >> 2) & 1) * 16 + ((p >> 3) & 3) * 4 + (p & 3);
            h[j] = (__bf16)T[k][d];
        }
        *(bf16x8*)(Vd + ((size_t)bt * 1024 + iu) * 8) = h;
    }
}

// ============================== main attention kernel ==============================
__device__ __forceinline__ void load_lds16(const __bf16* g, __bf16* l) {
    __builtin_amdgcn_global_load_lds(
        (const __attribute__((address_space(1))) void*)g,
        (__attribute__((address_space(3))) void*)l, 16, 0, 0);
}

#define WAIT_VM(N)                                                             \
    do {                                                                       \
        asm volatile("s_waitcnt vmcnt(" #N ")" ::: "memory");                  \
        __builtin_amdgcn_sched_barrier(0);                                     \
    } while (0)

#define BAR() __builtin_amdgcn_s_barrier()

// 4 global_load_lds issues per wave (2 K + 2 V), tile t2 -> buffer BUF
#define ISSUE_LDS(BUF, t2)                                                     \
    do {                                                                       \
        const size_t tb = (size_t)(bh * 32 + (t2)) * TILE_ELEMS;               \
        const __bf16* kg = Kimg + tb + w * 1024 + lane * 8;                    \
        const __bf16* vg = Vimg + tb + w * 1024 + lane * 8;                    \
        load_lds16(kg,       &Klds[BUF][w * 1024]);                            \
        load_lds16(kg + 512, &Klds[BUF][w * 1024 + 512]);                      \
        load_lds16(vg,       &Vlds[BUF][w * 1024]);                            \
        load_lds16(vg + 512, &Vlds[BUF][w * 1024 + 512]);                      \
    } while (0)

#define ISSUE_M(MST, t2)                                                       \
    do {                                                                       \
        _Pragma("unroll")                                                      \
        for (int kt = 0; kt < 4; ++kt)                                         \
            MST[kt] = *(const int4*)(mrow + (t2) * KVBLK + kt * 16 + lg * 4);  \
    } while (0)

#define COMPUTE_TILE(BUF, MST)                                                 \
    do {                                                                       \
        const __bf16* KL = Klds[BUF];                                          \
        const __bf16* VL = Vlds[BUF];                                          \
        f32x4 s[4];                                                            \
        __builtin_amdgcn_s_setprio(1);                                         \
        _Pragma("unroll")                                                      \
        for (int kt = 0; kt < 4; ++kt) {                                       \
            s[kt] = (f32x4)0.0f;                                               \
            _Pragma("unroll")                                                  \
            for (int d0 = 0; d0 < 4; ++d0) {                                   \
                bf16x8 kf = *(const bf16x8*)&KL[(kt * 16 + lr) * DD            \
                                                + ((d0 * 4 + lg) ^ sw) * 8];   \
                s[kt] = __builtin_amdgcn_mfma_f32_16x16x32_bf16(kf, qf[d0], s[kt], 0, 0, 0); \
            }                                                                  \
        }                                                                      \
        __builtin_amdgcn_s_setprio(0);                                         \
        float mx = -1e30f;                                                     \
        _Pragma("unroll")                                                      \
        for (int kt = 0; kt < 4; ++kt) {                                       \
            int4 mm = MST[kt];                                                 \
            s[kt][0] = s[kt][0] * scale2 + mcoef * (float)mm.x;                \
            s[kt][1] = s[kt][1] * scale2 + mcoef * (float)mm.y;                \
            s[kt][2] = s[kt][2] * scale2 + mcoef * (float)mm.z;                \
            s[kt][3] = s[kt][3] * scale2 + mcoef * (float)mm.w;                \
            mx = fmaxf(mx, fmaxf(fmaxf(s[kt][0], s[kt][1]),                    \
                                 fmaxf(s[kt][2], s[kt][3])));                  \
        }                                                                      \
        mx = fmaxf(mx, __shfl_xor(mx, 16));                                    \
        mx = fmaxf(mx, __shfl_xor(mx, 32));                                    \
        if (__any(mx > m2 + 11.5415603f)) {   /* defer-max: rarely taken */    \
            const float newm  = fmaxf(m2, mx);                                 \
            const float alpha = exp2f(m2 - newm);                              \
            m2 = newm;                                                         \
            l_i *= alpha;                                                      \
            _Pragma("unroll")                                                  \
            for (int dt = 0; dt < 8; ++dt) {                                   \
                o[dt][0] *= alpha; o[dt][1] *= alpha;                          \
                o[dt][2] *= alpha; o[dt][3] *= alpha;                          \
            }                                                                  \
        }                                                                      \
        float rs = 0.0f;                                                       \
        _Pragma("unroll")                                                      \
        for (int kt = 0; kt < 4; ++kt) {                                       \
            _Pragma("unroll")                                                  \
            for (int r = 0; r < 4; ++r) {                                      \
                const float p = exp2f(s[kt][r] - m2);                          \
                s[kt][r] = p;                                                  \
                rs += p;                                                       \
            }                                                                  \
        }                                                                      \
        rs += __shfl_xor(rs, 16);                                              \
        rs += __shfl_xor(rs, 32);                                              \
        l_i += rs;                                                             \
        __builtin_amdgcn_s_setprio(1);                                         \
        _Pragma("unroll")                                                      \
        for (int ch = 0; ch < 2; ++ch) {                                       \
            bf16x8 pb;                                                         \
            pb[0] = (__bf16)s[2*ch][0];   pb[1] = (__bf16)s[2*ch][1];          \
            pb[2] = (__bf16)s[2*ch][2];   pb[3] = (__bf16)s[2*ch][3];          \
            pb[4] = (__bf16)s[2*ch+1][0]; pb[5] = (__bf16)s[2*ch+1][1];        \
            pb[6] = (__bf16)s[2*ch+1][2]; pb[7] = (__bf16)s[2*ch+1][3];        \
            _Pragma("unroll")                                                  \
            for (int dt = 0; dt < 8; ++dt) {                                   \
                bf16x8 va = *(const bf16x8*)&VL[(dt * 16 + lr) * KVBLK         \
                                                + ((ch * 4 + lg) ^ sw) * 8];   \
                o[dt] = __builtin_amdgcn_mfma_f32_16x16x32_bf16(va, pb, o[dt], 0, 0, 0); \
            }                                                                  \
        }                                                                      \
        __builtin_amdgcn_s_setprio(0);                                         \
    } while (0)

#define HALF_ITER(BUF, MREG, tnext)                                            \
    do {                                                                       \
        COMPUTE_TILE(BUF, MREG);                                               \
        BAR();                                                                 \
        ISSUE_LDS(BUF, tnext);                                                 \
        ISSUE_M(MREG, tnext);                                                  \
        WAIT_VM(8);                                                            \
        BAR();                                                                 \
    } while (0)

__global__ __launch_bounds__(512, 4)
void attn_fwd(const float* __restrict__ Q, const __bf16* __restrict__ Kimg,
              const __bf16* __restrict__ Vimg, const int* __restrict__ M,
              float* __restrict__ O)
{
    __shared__ __bf16 Klds[2][TILE_ELEMS];
    __shared__ __bf16 Vlds[2][TILE_ELEMS];

    const int tid  = threadIdx.x;
    const int lane = tid & 63;
    const int lr   = lane & 15;
    const int lg   = lane >> 4;
    const int w    = tid >> 6;        // wave 0..7
    const int sw   = lr & 7;          // XOR-swizzle key (row&7 for all our LDS rows)

    // bijective XCD-chunked swizzle: nwg=512, 8 XCDs, 64 blocks/XCD
    const int bid = blockIdx.x;
    const int swz = (bid & 7) * 64 + (bid >> 3);
    const int qb  = swz & 15;         // 16 q-blocks per bh
    const int bh  = swz >> 4;
    const int b   = bh >> 4;

    const float scale2 = 0.08838834764831845f * 1.4426950408889634f; // /sqrt(d)*log2e
    const float mcoef  = -1.4426950408889634e9f;                     // -1e9*log2e

    const float* Qb = Q + (size_t)bh * SS * DD;
    const int*   Mb = M + (size_t)b * SS * SS;
    float*       Ob = O + (size_t)bh * SS * DD;

    const int  qrow = qb * QBLK + w * 16 + lr;
    const int* mrow = Mb + (size_t)qrow * SS;

    // ---- Q fragment (B-operand), loaded once ----
    bf16x8 qf[4];
    {
        const float* qr = Qb + (size_t)qrow * DD;
        #pragma unroll
        for (int d0 = 0; d0 < 4; ++d0) {
            float4 f0 = *(const float4*)(qr + d0 * 32 + lg * 8);
            float4 f1 = *(const float4*)(qr + d0 * 32 + lg * 8 + 4);
            bf16x8 a;
            a[0]=(__bf16)f0.x; a[1]=(__bf16)f0.y; a[2]=(__bf16)f0.z; a[3]=(__bf16)f0.w;
            a[4]=(__bf16)f1.x; a[5]=(__bf16)f1.y; a[6]=(__bf16)f1.z; a[7]=(__bf16)f1.w;
            qf[d0] = a;
        }
    }
    __builtin_amdgcn_sched_barrier(0);   // Q loads drained before pipeline starts

    f32x4 o[8];
    #pragma unroll
    for (int i = 0; i < 8; ++i) o[i] = (f32x4)0.0f;
    float m2 = -1e30f, l_i = 0.0f;

    int4 mA[4], mB[4];

    // ---- pipeline prologue: 2 tiles in flight ----
    ISSUE_LDS(0, 0);
    ISSUE_M(mA, 0);
    ISSUE_LDS(1, 1);
    ISSUE_M(mB, 1);
    WAIT_VM(8);     // tile-0 group landed; tile-1 group (8 ops) in flight
    BAR();

    // ---- main loop: counted vmcnt, never drained to 0 ----
    #pragma unroll 1
    for (int t = 0; t + 3 < NT; t += 2) {
        HALF_ITER(0, mA, t + 2);
        HALF_ITER(1, mB, t + 3);
    }
    // tail: t = NT-2, NT-1
    COMPUTE_TILE(0, mA);
    WAIT_VM(0);
    BAR();
    COMPUTE_TILE(1, mB);

    // ---- epilogue ----
    const float inv = 1.0f / l_i;
    float* orow = Ob + (size_t)qrow * DD;
    #pragma unroll
    for (int dt = 0; dt < 8; ++dt) {
        float4 st;
        st.x = o[dt][0] * inv; st.y = o[dt][1] * inv;
        st.z = o[dt][2] * inv; st.w = o[dt][3] * inv;
        *(float4*)&orow[dt * 16 + lg * 4] = st;
    }
}

extern "C" void kernel_launch(void* const* d_in, const int* in_sizes, int n_in,
                              void* d_out, int out_size, void* d_ws, size_t ws_size,
                              hipStream_t stream) {
    const float* Q = (const float*)d_in[0];
    const float* K = (const float*)d_in[1];
    const float* V = (const float*)d_in[2];
    const int*   M = (const int*)d_in[4];
    float*       O = (float*)d_out;

    __bf16* Kimg = (__bf16*)d_ws;                          // 16.78 MB
    __bf16* Vimg = Kimg + (size_t)BB * HH * SS * DD;       // 16.78 MB

    kimg_prep<<<1024, 256, 0, stream>>>(K, Kimg);
    vimg_prep<<<BB * HH * NT, 256, 0, stream>>>(V, Vimg);

    attn_fwd<<<BB * HH * (SS / QBLK), 512, 0, stream>>>(Q, Kimg, Vimg, M, O);
}

// Round 6
// 138.653 us; speedup vs baseline: 2.5512x; 1.0580x over previous
//
#include <hip/hip_runtime.h>
#include <hip/hip_bf16.h>

#define BB 2
#define HH 16
#define SS 2048
#define DD 128
#define QBLK 128
#define KVBLK 64
#define NT (SS / KVBLK)
#define TILE_ELEMS (KVBLK * DD)   // 8192 bf16 = 16 KB per K or V tile

typedef __bf16 bf16x8 __attribute__((ext_vector_type(8)));
typedef float  f32x4  __attribute__((ext_vector_type(4)));

// ============ pre-pass 1: K fp32 -> bf16 LDS-image (XOR-swizzled 16B units) ============
__global__ __launch_bounds__(256)
void kimg_prep(const float* __restrict__ K, __bf16* __restrict__ Kd)
{
    #pragma unroll
    for (int i = 0; i < 4; ++i) {
        const int g  = blockIdx.x * 1024 + i * 256 + threadIdx.x;
        const int tr = g >> 4;
        const int u  = (g & 15) ^ (tr & 7);
        const float* src = K + (size_t)tr * DD + u * 8;
        float4 f0 = *(const float4*)src;
        float4 f1 = *(const float4*)(src + 4);
        bf16x8 h;
        h[0]=(__bf16)f0.x; h[1]=(__bf16)f0.y; h[2]=(__bf16)f0.z; h[3]=(__bf16)f0.w;
        h[4]=(__bf16)f1.x; h[5]=(__bf16)f1.y; h[6]=(__bf16)f1.z; h[7]=(__bf16)f1.w;
        *(bf16x8*)(Kd + (size_t)g * 8) = h;
    }
}

// ===== pre-pass 2: V fp32 [s][d] -> bf16 V^T LDS-image (k-slot permuted + XOR) =====
__global__ __launch_bounds__(256)
void vimg_prep(const float* __restrict__ V, __bf16* __restrict__ Vd)
{
    __shared__ float T[KVBLK][DD + 4];
    const int bt = blockIdx.x;                       // bh*32 + tile
    const float* src = V + (size_t)bt * KVBLK * DD;
    #pragma unroll
    for (int i = 0; i < 8; ++i) {
        const int idx = i * 256 + threadIdx.x;       // 0..2047
        const int r = idx >> 5, c4 = idx & 31;
        float4 f = *(const float4*)(src + (size_t)r * DD + c4 * 4);
        T[r][c4 * 4 + 0] = f.x; T[r][c4 * 4 + 1] = f.y;
        T[r][c4 * 4 + 2] = f.z; T[r][c4 * 4 + 3] = f.w;
    }
    __syncthreads();
    #pragma unroll
    for (int i = 0; i < 4; ++i) {
        const int iu = i * 256 + threadIdx.x;        // 0..1023
        const int d  = iu >> 3;
        const int pu = (iu & 7) ^ (d & 7);
        bf16x8 h;
        #pragma unroll
        for (int j = 0; j < 8; ++j) {
            const int p = pu * 8 + j;
            const int k = (p >> 5) * 32 + ((p >> 2) & 1) * 16 + ((p >> 3) & 3) * 4 + (p & 3);
            h[j] = (__bf16)T[k][d];
        }
        *(bf16x8*)(Vd + ((size_t)bt * 1024 + iu) * 8) = h;
    }
}

// ============================== main attention kernel ==============================
__device__ __forceinline__ void load_lds16(const __bf16* g, __bf16* l) {
    __builtin_amdgcn_global_load_lds(
        (const __attribute__((address_space(1))) void*)g,
        (__attribute__((address_space(3))) void*)l, 16, 0, 0);
}

#define WAIT_VM(N)                                                             \
    do {                                                                       \
        asm volatile("s_waitcnt vmcnt(" #N ")" ::: "memory");                  \
        __builtin_amdgcn_sched_barrier(0);                                     \
    } while (0)

#define BAR() __builtin_amdgcn_s_barrier()

// 4 global_load_lds issues per wave (2 K + 2 V), tile t2 -> buffer BUF (literal!)
#define ISSUE_LDS(BUF, t2)                                                     \
    do {                                                                       \
        const size_t tb = (size_t)(bh * 32 + (t2)) * TILE_ELEMS;               \
        const __bf16* kg = Kimg + tb + w * 1024 + lane * 8;                    \
        const __bf16* vg = Vimg + tb + w * 1024 + lane * 8;                    \
        load_lds16(kg,       smKw + (BUF) * TILE_ELEMS);                       \
        load_lds16(kg + 512, smKw + (BUF) * TILE_ELEMS + 512);                 \
        load_lds16(vg,       smVw + (BUF) * TILE_ELEMS);                       \
        load_lds16(vg + 512, smVw + (BUF) * TILE_ELEMS + 512);                 \
    } while (0)

#define ISSUE_M(MST, t2)                                                       \
    do {                                                                       \
        _Pragma("unroll")                                                      \
        for (int kt = 0; kt < 4; ++kt)                                         \
            MST[kt] = *(const int4*)(mlane + (t2) * KVBLK + kt * 16);          \
    } while (0)

// all ds_read addresses = precomputed lane base + compile-time offset
#define COMPUTE_TILE(BUF, MST)                                                 \
    do {                                                                       \
        f32x4 s[4];                                                            \
        __builtin_amdgcn_s_setprio(1);                                         \
        _Pragma("unroll")                                                      \
        for (int kt = 0; kt < 4; ++kt) {                                       \
            s[kt] = (f32x4)0.0f;                                               \
            _Pragma("unroll")                                                  \
            for (int d0 = 0; d0 < 4; ++d0) {                                   \
                bf16x8 kf = *(const bf16x8*)(kpE[d0] + (BUF) * TILE_ELEMS      \
                                             + kt * 16 * DD);                  \
                s[kt] = __builtin_amdgcn_mfma_f32_16x16x32_bf16(kf, qf[d0], s[kt], 0, 0, 0); \
            }                                                                  \
        }                                                                      \
        __builtin_amdgcn_s_setprio(0);                                         \
        float mx = -1e30f;                                                     \
        _Pragma("unroll")                                                      \
        for (int kt = 0; kt < 4; ++kt) {                                       \
            int4 mm = MST[kt];                                                 \
            s[kt][0] += mcoef * (float)mm.x;                                   \
            s[kt][1] += mcoef * (float)mm.y;                                   \
            s[kt][2] += mcoef * (float)mm.z;                                   \
            s[kt][3] += mcoef * (float)mm.w;                                   \
            mx = fmaxf(fmaxf(mx, fmaxf(s[kt][0], s[kt][1])),                   \
                       fmaxf(s[kt][2], s[kt][3]));                             \
        }                                                                      \
        mx = fmaxf(mx, __shfl_xor(mx, 16));                                    \
        mx = fmaxf(mx, __shfl_xor(mx, 32));                                    \
        if (__any(mx > m2 + 11.5415603f)) {   /* defer-max: rarely taken */    \
            const float newm  = fmaxf(m2, mx);                                 \
            const float alpha = exp2f(m2 - newm);                              \
            m2 = newm;                                                         \
            l_i *= alpha;                                                      \
            _Pragma("unroll")                                                  \
            for (int dt = 0; dt < 8; ++dt) {                                   \
                o[dt][0] *= alpha; o[dt][1] *= alpha;                          \
                o[dt][2] *= alpha; o[dt][3] *= alpha;                          \
            }                                                                  \
        }                                                                      \
        float rs = 0.0f;                                                       \
        _Pragma("unroll")                                                      \
        for (int kt = 0; kt < 4; ++kt) {                                       \
            _Pragma("unroll")                                                  \
            for (int r = 0; r < 4; ++r) {                                      \
                const float p = exp2f(s[kt][r] - m2);                          \
                s[kt][r] = p;                                                  \
                rs += p;                                                       \
            }                                                                  \
        }                                                                      \
        rs += __shfl_xor(rs, 16);                                              \
        rs += __shfl_xor(rs, 32);                                              \
        l_i += rs;                                                             \
        __builtin_amdgcn_s_setprio(1);                                         \
        _Pragma("unroll")                                                      \
        for (int ch = 0; ch < 2; ++ch) {                                       \
            bf16x8 pb;                                                         \
            pb[0] = (__bf16)s[2*ch][0];   pb[1] = (__bf16)s[2*ch][1];          \
            pb[2] = (__bf16)s[2*ch][2];   pb[3] = (__bf16)s[2*ch][3];          \
            pb[4] = (__bf16)s[2*ch+1][0]; pb[5] = (__bf16)s[2*ch+1][1];        \
            pb[6] = (__bf16)s[2*ch+1][2]; pb[7] = (__bf16)s[2*ch+1][3];        \
            _Pragma("unroll")                                                  \
            for (int dt = 0; dt < 8; ++dt) {                                   \
                bf16x8 va = *(const bf16x8*)(vpE[ch] + (BUF) * TILE_ELEMS      \
                                             + dt * 16 * KVBLK);               \
                o[dt] = __builtin_amdgcn_mfma_f32_16x16x32_bf16(va, pb, o[dt], 0, 0, 0); \
            }                                                                  \
        }                                                                      \
        __builtin_amdgcn_s_setprio(0);                                         \
    } while (0)

#define HALF_ITER(BUF, MREG, tnext)                                            \
    do {                                                                       \
        COMPUTE_TILE(BUF, MREG);                                               \
        BAR();                                                                 \
        ISSUE_LDS(BUF, tnext);                                                 \
        ISSUE_M(MREG, tnext);                                                  \
        WAIT_VM(8);                                                            \
        BAR();                                                                 \
    } while (0)

__global__ __launch_bounds__(512, 4)
void attn_fwd(const float* __restrict__ Q, const __bf16* __restrict__ Kimg,
              const __bf16* __restrict__ Vimg, const int* __restrict__ M,
              float* __restrict__ O)
{
    // flat LDS: [K buf0 | K buf1 | V buf0 | V buf1], 64 KB total
    __shared__ __bf16 SM[4 * TILE_ELEMS];

    const int tid  = threadIdx.x;
    const int lane = tid & 63;
    const int lr   = lane & 15;
    const int lg   = lane >> 4;
    const int w    = tid >> 6;        // wave 0..7
    const int sw   = lr & 7;          // XOR-swizzle key (= row&7 for our LDS rows)

    // bijective XCD-chunked swizzle: nwg=512, 8 XCDs, 64 blocks/XCD
    const int bid = blockIdx.x;
    const int swz = (bid & 7) * 64 + (bid >> 3);
    const int qb  = swz & 15;         // 16 q-blocks per bh
    const int bh  = swz >> 4;
    const int b   = bh >> 4;

    const float SC    = 0.08838834764831845f * 1.4426950408889634f; // /sqrt(d)*log2e
    const float mcoef = -1.4426950408889634e9f;                     // -1e9*log2e

    const float* Qb = Q + (size_t)bh * SS * DD;
    const int*   Mb = M + (size_t)b * SS * SS;
    float*       Ob = O + (size_t)bh * SS * DD;

    const int  qrow  = qb * QBLK + w * 16 + lr;
    const int* mlane = Mb + (size_t)qrow * SS + lg * 4;

    // ---- precomputed LDS lane bases (the whole point of this round) ----
    const int swl3 = (lg ^ sw) & 3;   // lg ^ (sw&3)
    const int swh  = sw >> 2;
    const __bf16* kpE[4];
    #pragma unroll
    for (int d0 = 0; d0 < 4; ++d0)
        kpE[d0] = SM + lr * DD + (((d0 ^ swh) << 2) + swl3) * 8;
    const __bf16* vpE[2];
    #pragma unroll
    for (int ch = 0; ch < 2; ++ch)
        vpE[ch] = SM + 2 * TILE_ELEMS + lr * KVBLK + (((ch ^ swh) << 2) + swl3) * 8;
    __bf16* smKw = SM + w * 1024;                    // wave-uniform glds dests
    __bf16* smVw = SM + 2 * TILE_ELEMS + w * 1024;

    // ---- Q fragment (B-operand), pre-scaled by SC, loaded once ----
    bf16x8 qf[4];
    {
        const float* qr = Qb + (size_t)qrow * DD;
        #pragma unroll
        for (int d0 = 0; d0 < 4; ++d0) {
            float4 f0 = *(const float4*)(qr + d0 * 32 + lg * 8);
            float4 f1 = *(const float4*)(qr + d0 * 32 + lg * 8 + 4);
            bf16x8 a;
            a[0]=(__bf16)(f0.x*SC); a[1]=(__bf16)(f0.y*SC);
            a[2]=(__bf16)(f0.z*SC); a[3]=(__bf16)(f0.w*SC);
            a[4]=(__bf16)(f1.x*SC); a[5]=(__bf16)(f1.y*SC);
            a[6]=(__bf16)(f1.z*SC); a[7]=(__bf16)(f1.w*SC);
            qf[d0] = a;
        }
    }
    __builtin_amdgcn_sched_barrier(0);   // Q loads drained before pipeline starts

    f32x4 o[8];
    #pragma unroll
    for (int i = 0; i < 8; ++i) o[i] = (f32x4)0.0f;
    float m2 = -1e30f, l_i = 0.0f;

    int4 mA[4], mB[4];

    // ---- pipeline prologue: 2 tiles in flight ----
    ISSUE_LDS(0, 0);
    ISSUE_M(mA, 0);
    ISSUE_LDS(1, 1);
    ISSUE_M(mB, 1);
    WAIT_VM(8);     // tile-0 group landed; tile-1 group (8 ops) in flight
    BAR();

    // ---- main loop: counted vmcnt, never drained to 0 ----
    #pragma unroll 1
    for (int t = 0; t + 3 < NT; t += 2) {
        HALF_ITER(0, mA, t + 2);
        HALF_ITER(1, mB, t + 3);
    }
    // tail: tiles NT-2, NT-1
    COMPUTE_TILE(0, mA);
    WAIT_VM(0);
    BAR();
    COMPUTE_TILE(1, mB);

    // ---- epilogue ----
    const float inv = 1.0f / l_i;
    float* orow = Ob + (size_t)qrow * DD;
    #pragma unroll
    for (int dt = 0; dt < 8; ++dt) {
        float4 st;
        st.x = o[dt][0] * inv; st.y = o[dt][1] * inv;
        st.z = o[dt][2] * inv; st.w = o[dt][3] * inv;
        *(float4*)&orow[dt * 16 + lg * 4] = st;
    }
}

extern "C" void kernel_launch(void* const* d_in, const int* in_sizes, int n_in,
                              void* d_out, int out_size, void* d_ws, size_t ws_size,
                              hipStream_t stream) {
    const float* Q = (const float*)d_in[0];
    const float* K = (const float*)d_in[1];
    const float* V = (const float*)d_in[2];
    const int*   M = (const int*)d_in[4];
    float*       O = (float*)d_out;

    __bf16* Kimg = (__bf16*)d_ws;                          // 16.78 MB
    __bf16* Vimg = Kimg + (size_t)BB * HH * SS * DD;       // 16.78 MB

    kimg_prep<<<1024, 256, 0, stream>>>(K, Kimg);
    vimg_prep<<<BB * HH * NT, 256, 0, stream>>>(V, Vimg);

    attn_fwd<<<BB * HH * (SS / QBLK), 512, 0, stream>>>(Q, Kimg, Vimg, M, O);
}

// Round 7
// 136.008 us; speedup vs baseline: 2.6008x; 1.0194x over previous
//
#include <hip/hip_runtime.h>
#include <hip/hip_bf16.h>

#define BB 2
#define HH 16
#define SS 2048
#define DD 128
#define QBLK 128
#define KVBLK 64
#define NT (SS / KVBLK)
#define TILE_ELEMS (KVBLK * DD)   // 8192 bf16 = 16 KB per K or V tile

typedef __bf16 bf16x8 __attribute__((ext_vector_type(8)));
typedef float  f32x4  __attribute__((ext_vector_type(4)));

#define EXP2(x) __builtin_amdgcn_exp2f(x)

// ============ pre-pass 1: K fp32 -> bf16 LDS-image (XOR-swizzled 16B units) ============
__global__ __launch_bounds__(256)
void kimg_prep(const float* __restrict__ K, __bf16* __restrict__ Kd)
{
    #pragma unroll
    for (int i = 0; i < 4; ++i) {
        const int g  = blockIdx.x * 1024 + i * 256 + threadIdx.x;
        const int tr = g >> 4;
        const int u  = (g & 15) ^ (tr & 7);
        const float* src = K + (size_t)tr * DD + u * 8;
        float4 f0 = *(const float4*)src;
        float4 f1 = *(const float4*)(src + 4);
        bf16x8 h;
        h[0]=(__bf16)f0.x; h[1]=(__bf16)f0.y; h[2]=(__bf16)f0.z; h[3]=(__bf16)f0.w;
        h[4]=(__bf16)f1.x; h[5]=(__bf16)f1.y; h[6]=(__bf16)f1.z; h[7]=(__bf16)f1.w;
        *(bf16x8*)(Kd + (size_t)g * 8) = h;
    }
}

// ===== pre-pass 2: V fp32 [s][d] -> bf16 V^T LDS-image (k-slot permuted + XOR) =====
__global__ __launch_bounds__(256)
void vimg_prep(const float* __restrict__ V, __bf16* __restrict__ Vd)
{
    __shared__ float T[KVBLK][DD + 4];
    const int bt = blockIdx.x;                       // bh*32 + tile
    const float* src = V + (size_t)bt * KVBLK * DD;
    #pragma unroll
    for (int i = 0; i < 8; ++i) {
        const int idx = i * 256 + threadIdx.x;       // 0..2047
        const int r = idx >> 5, c4 = idx & 31;
        float4 f = *(const float4*)(src + (size_t)r * DD + c4 * 4);
        T[r][c4 * 4 + 0] = f.x; T[r][c4 * 4 + 1] = f.y;
        T[r][c4 * 4 + 2] = f.z; T[r][c4 * 4 + 3] = f.w;
    }
    __syncthreads();
    #pragma unroll
    for (int i = 0; i < 4; ++i) {
        const int iu = i * 256 + threadIdx.x;        // 0..1023
        const int d  = iu >> 3;
        const int pu = (iu & 7) ^ (d & 7);
        bf16x8 h;
        #pragma unroll
        for (int j = 0; j < 8; ++j) {
            const int p = pu * 8 + j;
            const int k = (p >> 5) * 32 + ((p >> 2) & 1) * 16 + ((p >> 3) & 3) * 4 + (p & 3);
            h[j] = (__bf16)T[k][d];
        }
        *(bf16x8*)(Vd + ((size_t)bt * 1024 + iu) * 8) = h;
    }
}

// ============================== main attention kernel ==============================
__device__ __forceinline__ void load_lds16(const __bf16* g, __bf16* l) {
    __builtin_amdgcn_global_load_lds(
        (const __attribute__((address_space(1))) void*)g,
        (__attribute__((address_space(3))) void*)l, 16, 0, 0);
}

#define WAIT_VM(N)                                                             \
    do {                                                                       \
        asm volatile("s_waitcnt vmcnt(" #N ")" ::: "memory");                  \
        __builtin_amdgcn_sched_barrier(0);                                     \
    } while (0)

#define BAR() __builtin_amdgcn_s_barrier()

// next-tile issue via running pointers (advanced inside)
#define ISSUE_LDS(BUF)                                                         \
    do {                                                                       \
        load_lds16(kgp,       smKw + (BUF) * TILE_ELEMS);                      \
        load_lds16(kgp + 512, smKw + (BUF) * TILE_ELEMS + 512);                \
        load_lds16(vgp,       smVw + (BUF) * TILE_ELEMS);                      \
        load_lds16(vgp + 512, smVw + (BUF) * TILE_ELEMS + 512);                \
        kgp += TILE_ELEMS;                                                     \
        vgp += TILE_ELEMS;                                                     \
    } while (0)

#define ISSUE_M(MST)                                                           \
    do {                                                                       \
        _Pragma("unroll")                                                      \
        for (int kt = 0; kt < 4; ++kt)                                         \
            MST[kt] = *(const int4*)(mp + kt * 16);                            \
        mp += KVBLK;                                                           \
    } while (0)

// all ds_read addresses = precomputed lane base + compile-time offset
#define COMPUTE_TILE(BUF, MST)                                                 \
    do {                                                                       \
        f32x4 s[4];                                                            \
        __builtin_amdgcn_s_setprio(1);                                         \
        _Pragma("unroll")                                                      \
        for (int kt = 0; kt < 4; ++kt) {                                       \
            s[kt] = (f32x4)0.0f;                                               \
            _Pragma("unroll")                                                  \
            for (int d0 = 0; d0 < 4; ++d0) {                                   \
                bf16x8 kf = *(const bf16x8*)(kpE[d0] + (BUF) * TILE_ELEMS      \
                                             + kt * 16 * DD);                  \
                s[kt] = __builtin_amdgcn_mfma_f32_16x16x32_bf16(kf, qf[d0], s[kt], 0, 0, 0); \
            }                                                                  \
        }                                                                      \
        __builtin_amdgcn_s_setprio(0);                                         \
        /* mx over RAW scores (>= true unmasked max; scaling cancels) */       \
        float mx = fmaxf(fmaxf(s[0][0], s[0][1]), fmaxf(s[0][2], s[0][3]));    \
        _Pragma("unroll")                                                      \
        for (int kt = 1; kt < 4; ++kt)                                         \
            mx = fmaxf(fmaxf(mx, fmaxf(s[kt][0], s[kt][1])),                   \
                       fmaxf(s[kt][2], s[kt][3]));                             \
        mx = fmaxf(mx, __shfl_xor(mx, 16));                                    \
        mx = fmaxf(mx, __shfl_xor(mx, 32));                                    \
        if (__any(mx > m2 + 11.5415603f)) {   /* defer-max: rarely taken */    \
            const float newm  = fmaxf(m2, mx);                                 \
            const float alpha = EXP2(m2 - newm);                               \
            m2 = newm;                                                         \
            l_i *= alpha;                                                      \
            _Pragma("unroll")                                                  \
            for (int dt = 0; dt < 8; ++dt) {                                   \
                o[dt][0] *= alpha; o[dt][1] *= alpha;                          \
                o[dt][2] *= alpha; o[dt][3] *= alpha;                          \
            }                                                                  \
        }                                                                      \
        float rs = 0.0f;                                                       \
        _Pragma("unroll")                                                      \
        for (int kt = 0; kt < 4; ++kt) {                                       \
            int4 mm = MST[kt];                                                 \
            float p0 = EXP2(s[kt][0] - m2);                                    \
            float p1 = EXP2(s[kt][1] - m2);                                    \
            float p2 = EXP2(s[kt][2] - m2);                                    \
            float p3 = EXP2(s[kt][3] - m2);                                    \
            p0 = mm.x ? 0.0f : p0;                                             \
            p1 = mm.y ? 0.0f : p1;                                             \
            p2 = mm.z ? 0.0f : p2;                                             \
            p3 = mm.w ? 0.0f : p3;                                             \
            s[kt][0] = p0; s[kt][1] = p1; s[kt][2] = p2; s[kt][3] = p3;        \
            rs += (p0 + p1) + (p2 + p3);                                       \
        }                                                                      \
        rs += __shfl_xor(rs, 16);                                              \
        rs += __shfl_xor(rs, 32);                                              \
        l_i += rs;                                                             \
        __builtin_amdgcn_s_setprio(1);                                         \
        _Pragma("unroll")                                                      \
        for (int ch = 0; ch < 2; ++ch) {                                       \
            bf16x8 pb;                                                         \
            pb[0] = (__bf16)s[2*ch][0];   pb[1] = (__bf16)s[2*ch][1];          \
            pb[2] = (__bf16)s[2*ch][2];   pb[3] = (__bf16)s[2*ch][3];          \
            pb[4] = (__bf16)s[2*ch+1][0]; pb[5] = (__bf16)s[2*ch+1][1];        \
            pb[6] = (__bf16)s[2*ch+1][2]; pb[7] = (__bf16)s[2*ch+1][3];        \
            _Pragma("unroll")                                                  \
            for (int dt = 0; dt < 8; ++dt) {                                   \
                bf16x8 va = *(const bf16x8*)(vpE[ch] + (BUF) * TILE_ELEMS      \
                                             + dt * 16 * KVBLK);               \
                o[dt] = __builtin_amdgcn_mfma_f32_16x16x32_bf16(va, pb, o[dt], 0, 0, 0); \
            }                                                                  \
        }                                                                      \
        __builtin_amdgcn_s_setprio(0);                                         \
    } while (0)

#define HALF_ITER(BUF, MREG)                                                   \
    do {                                                                       \
        COMPUTE_TILE(BUF, MREG);                                               \
        BAR();                                                                 \
        ISSUE_LDS(BUF);                                                        \
        ISSUE_M(MREG);                                                         \
        WAIT_VM(8);                                                            \
        BAR();                                                                 \
    } while (0)

__global__ __launch_bounds__(512, 4)
void attn_fwd(const float* __restrict__ Q, const __bf16* __restrict__ Kimg,
              const __bf16* __restrict__ Vimg, const int* __restrict__ M,
              float* __restrict__ O)
{
    // flat LDS: [K buf0 | K buf1 | V buf0 | V buf1], 64 KB total
    __shared__ __bf16 SM[4 * TILE_ELEMS];

    const int tid  = threadIdx.x;
    const int lane = tid & 63;
    const int lr   = lane & 15;
    const int lg   = lane >> 4;
    const int w    = tid >> 6;        // wave 0..7
    const int sw   = lr & 7;          // XOR-swizzle key (= row&7 for our LDS rows)

    // bijective XCD-chunked swizzle: nwg=512, 8 XCDs, 64 blocks/XCD
    const int bid = blockIdx.x;
    const int swz = (bid & 7) * 64 + (bid >> 3);
    const int qb  = swz & 15;         // 16 q-blocks per bh
    const int bh  = swz >> 4;
    const int b   = bh >> 4;

    const float SC = 0.08838834764831845f * 1.4426950408889634f; // /sqrt(d)*log2e

    const float* Qb = Q + (size_t)bh * SS * DD;
    const int*   Mb = M + (size_t)b * SS * SS;
    float*       Ob = O + (size_t)bh * SS * DD;

    const int qrow = qb * QBLK + w * 16 + lr;

    // ---- running global pointers (advanced per tile) ----
    const __bf16* kgp = Kimg + (size_t)bh * 32 * TILE_ELEMS + w * 1024 + lane * 8;
    const __bf16* vgp = Vimg + (size_t)bh * 32 * TILE_ELEMS + w * 1024 + lane * 8;
    const int*    mp  = Mb + (size_t)qrow * SS + lg * 4;

    // ---- precomputed LDS lane bases ----
    const int swl3 = (lg ^ sw) & 3;
    const int swh  = sw >> 2;
    const __bf16* kpE[4];
    #pragma unroll
    for (int d0 = 0; d0 < 4; ++d0)
        kpE[d0] = SM + lr * DD + (((d0 ^ swh) << 2) + swl3) * 8;
    const __bf16* vpE[2];
    #pragma unroll
    for (int ch = 0; ch < 2; ++ch)
        vpE[ch] = SM + 2 * TILE_ELEMS + lr * KVBLK + (((ch ^ swh) << 2) + swl3) * 8;
    __bf16* smKw = SM + w * 1024;                    // wave-uniform glds dests
    __bf16* smVw = SM + 2 * TILE_ELEMS + w * 1024;

    // ---- Q fragment (B-operand), pre-scaled by SC, loaded once ----
    bf16x8 qf[4];
    {
        const float* qr = Qb + (size_t)qrow * DD;
        #pragma unroll
        for (int d0 = 0; d0 < 4; ++d0) {
            float4 f0 = *(const float4*)(qr + d0 * 32 + lg * 8);
            float4 f1 = *(const float4*)(qr + d0 * 32 + lg * 8 + 4);
            bf16x8 a;
            a[0]=(__bf16)(f0.x*SC); a[1]=(__bf16)(f0.y*SC);
            a[2]=(__bf16)(f0.z*SC); a[3]=(__bf16)(f0.w*SC);
            a[4]=(__bf16)(f1.x*SC); a[5]=(__bf16)(f1.y*SC);
            a[6]=(__bf16)(f1.z*SC); a[7]=(__bf16)(f1.w*SC);
            qf[d0] = a;
        }
    }
    __builtin_amdgcn_sched_barrier(0);   // Q loads drained before pipeline starts

    f32x4 o[8];
    #pragma unroll
    for (int i = 0; i < 8; ++i) o[i] = (f32x4)0.0f;
    float m2 = -1e30f, l_i = 0.0f;

    int4 mA[4], mB[4];

    // ---- pipeline prologue: 2 tiles in flight ----
    ISSUE_LDS(0);
    ISSUE_M(mA);
    ISSUE_LDS(1);
    ISSUE_M(mB);
    WAIT_VM(8);     // tile-0 group landed; tile-1 group (8 ops) in flight
    BAR();

    // ---- main loop: counted vmcnt, never drained to 0 ----
    #pragma unroll 1
    for (int t = 0; t + 3 < NT; t += 2) {
        HALF_ITER(0, mA);
        HALF_ITER(1, mB);
    }
    // tail: tiles NT-2, NT-1
    COMPUTE_TILE(0, mA);
    WAIT_VM(0);
    BAR();
    COMPUTE_TILE(1, mB);

    // ---- epilogue ----
    const float inv = 1.0f / l_i;
    float* orow = Ob + (size_t)qrow * DD;
    #pragma unroll
    for (int dt = 0; dt < 8; ++dt) {
        float4 st;
        st.x = o[dt][0] * inv; st.y = o[dt][1] * inv;
        st.z = o[dt][2] * inv; st.w = o[dt][3] * inv;
        *(float4*)&orow[dt * 16 + lg * 4] = st;
    }
}

extern "C" void kernel_launch(void* const* d_in, const int* in_sizes, int n_in,
                              void* d_out, int out_size, void* d_ws, size_t ws_size,
                              hipStream_t stream) {
    const float* Q = (const float*)d_in[0];
    const float* K = (const float*)d_in[1];
    const float* V = (const float*)d_in[2];
    const int*   M = (const int*)d_in[4];
    float*       O = (float*)d_out;

    __bf16* Kimg = (__bf16*)d_ws;                          // 16.78 MB
    __bf16* Vimg = Kimg + (size_t)BB * HH * SS * DD;       // 16.78 MB

    kimg_prep<<<1024, 256, 0, stream>>>(K, Kimg);
    vimg_prep<<<BB * HH * NT, 256, 0, stream>>>(V, Vimg);

    attn_fwd<<<BB * HH * (SS / QBLK), 512, 0, stream>>>(Q, Kimg, Vimg, M, O);
}

// Round 8
// 134.901 us; speedup vs baseline: 2.6222x; 1.0082x over previous
//
#include <hip/hip_runtime.h>
#include <hip/hip_bf16.h>

#define BB 2
#define HH 16
#define SS 2048
#define DD 128
#define QBLK 256
#define KVBLK 128
#define NT (SS / KVBLK)            // 16
#define TILE_ELEMS (KVBLK * DD)    // 16384 bf16 = 32 KB per K or V tile

typedef __bf16 bf16x8 __attribute__((ext_vector_type(8)));
typedef float  f32x16 __attribute__((ext_vector_type(16)));

#define EXP2(x) __builtin_amdgcn_exp2f(x)

// ============ pre-pass 1: K fp32 -> bf16 tile-flat LDS-image (unit XOR swizzle) ============
// tile = 128 rows x 16 units(16B); stored unit (row,u') holds K[row][( u'^(row&7) )*8 ..+8]
__global__ __launch_bounds__(256)
void kimg_prep(const float* __restrict__ K, __bf16* __restrict__ Kd)
{
    #pragma unroll
    for (int i = 0; i < 4; ++i) {
        const int g    = blockIdx.x * 1024 + i * 256 + threadIdx.x;  // unit id
        const int tile = g >> 11;
        const int wu   = g & 2047;
        const int row  = wu >> 4;
        const int u    = (wu & 15) ^ (row & 7);
        const float* src = K + ((size_t)tile * 128 + row) * 128 + u * 8;
        float4 f0 = *(const float4*)src;
        float4 f1 = *(const float4*)(src + 4);
        bf16x8 h;
        h[0]=(__bf16)f0.x; h[1]=(__bf16)f0.y; h[2]=(__bf16)f0.z; h[3]=(__bf16)f0.w;
        h[4]=(__bf16)f1.x; h[5]=(__bf16)f1.y; h[6]=(__bf16)f1.z; h[7]=(__bf16)f1.w;
        *(bf16x8*)(Kd + (size_t)g * 8) = h;
    }
}

// ===== pre-pass 2: V -> V^T tile image; unit (d,iu): sem-unit us=iu^(d&7), c=us>>1, h=us&1
// elem j holds V[tile*128 + c*16 + (j&3)+8*(j>>2)+4h][d]   (k-slot map matches PV B-operand)
__global__ __launch_bounds__(256)
void vimg_prep(const float* __restrict__ V, __bf16* __restrict__ Vd)
{
    const int g    = blockIdx.x * 256 + threadIdx.x;   // unit id, total 1,048,576
    const int tile = g >> 11;
    const int wu   = g & 2047;
    const int d    = wu & 127;
    const int iu   = wu >> 7;
    const int us   = iu ^ (d & 7);
    const int c    = us >> 1;
    const int h    = us & 1;
    const float* src = V + ((size_t)tile * 128 + c * 16 + 4 * h) * 128 + d;
    bf16x8 o;
    #pragma unroll
    for (int j = 0; j < 8; ++j) {
        const int roff = (j & 3) + 8 * (j >> 2);       // + base row c*16+4h
        o[j] = (__bf16)src[(size_t)roff * 128];
    }
    *(bf16x8*)(Vd + (size_t)tile * 16384 + ((size_t)d * 16 + iu) * 8) = o;
}

// ============ pre-pass 3: mask int32 -> bit-packed words (ballot) ============
__global__ __launch_bounds__(256)
void mprep(const int* __restrict__ M, unsigned* __restrict__ mb)
{
    const int wid  = blockIdx.x * 4 + (threadIdx.x >> 6);  // 131072 waves
    const int lane = threadIdx.x & 63;
    const int kb   = wid & 31;
    const int q    = (wid >> 5) & 2047;
    const int b    = wid >> 16;
    const int mi   = M[((size_t)b * 2048 + q) * 2048 + kb * 64 + lane];
    const unsigned long long bal = __ballot(mi != 0);
    if (lane == 0) {
        uint2 st; st.x = (unsigned)bal; st.y = (unsigned)(bal >> 32);
        *(uint2*)&mb[((size_t)b * 2048 + q) * 64 + kb * 2] = st;
    }
}

// ============================== main attention kernel ==============================
__device__ __forceinline__ void load_lds16(const __bf16* g, __bf16* l) {
    __builtin_amdgcn_global_load_lds(
        (const __attribute__((address_space(1))) void*)g,
        (__attribute__((address_space(3))) void*)l, 16, 0, 0);
}

#define WAIT_VM(N)                                                             \
    do {                                                                       \
        asm volatile("s_waitcnt vmcnt(" #N ")" ::: "memory");                  \
        __builtin_amdgcn_sched_barrier(0);                                     \
    } while (0)

#define BAR() __builtin_amdgcn_s_barrier()

// 8 glds issues per wave (4 K + 4 V) + advance
#define ISSUE_LDS(BUF)                                                         \
    do {                                                                       \
        _Pragma("unroll")                                                      \
        for (int i = 0; i < 4; ++i)                                            \
            load_lds16(kgp + i * 512, SM + (BUF) * 16384 + w * 2048 + i * 512);\
        _Pragma("unroll")                                                      \
        for (int i = 0; i < 4; ++i)                                            \
            load_lds16(vgp + i * 512, SM + 32768 + (BUF) * 16384 + w * 2048 + i * 512); \
        kgp += TILE_ELEMS;                                                     \
        vgp += TILE_ELEMS;                                                     \
    } while (0)

#define ISSUE_M(MST)                                                           \
    do { MST = *(const int4*)mp; mp += 4; } while (0)

#define COMPUTE_TILE(BUF, MST)                                                 \
    do {                                                                       \
        f32x16 s[4];                                                           \
        __builtin_amdgcn_s_setprio(1);                                         \
        _Pragma("unroll")                                                      \
        for (int ko = 0; ko < 4; ++ko) {                                       \
            s[ko] = (f32x16)0.0f;                                              \
            _Pragma("unroll")                                                  \
            for (int d0 = 0; d0 < 8; ++d0) {                                   \
                bf16x8 kf = *(const bf16x8*)(kp[d0] + (BUF) * 16384 + ko * 4096); \
                s[ko] = __builtin_amdgcn_mfma_f32_32x32x16_bf16(kf, qf[d0], s[ko], 0, 0, 0); \
            }                                                                  \
        }                                                                      \
        __builtin_amdgcn_s_setprio(0);                                         \
        float mx = s[0][0];                                                    \
        _Pragma("unroll")                                                      \
        for (int ko = 0; ko < 4; ++ko)                                         \
            _Pragma("unroll")                                                  \
            for (int j = (ko ? 0 : 1); j < 16; ++j) mx = fmaxf(mx, s[ko][j]);  \
        mx = fmaxf(mx, __shfl_xor(mx, 32));                                    \
        if (__any(mx > m2 + 11.5415603f)) {   /* defer-max: rarely taken */    \
            const float newm  = fmaxf(m2, mx);                                 \
            const float alpha = EXP2(m2 - newm);                               \
            m2 = newm;                                                         \
            l_i *= alpha;                                                      \
            _Pragma("unroll")                                                  \
            for (int dd = 0; dd < 4; ++dd)                                     \
                _Pragma("unroll")                                              \
                for (int j = 0; j < 16; ++j) o[dd][j] *= alpha;                \
        }                                                                      \
        float rs = 0.0f;                                                       \
        {                                                                      \
            const unsigned mw0 = ((unsigned)MST.x) >> sh4;                     \
            const unsigned mw1 = ((unsigned)MST.y) >> sh4;                     \
            const unsigned mw2 = ((unsigned)MST.z) >> sh4;                     \
            const unsigned mw3 = ((unsigned)MST.w) >> sh4;                     \
            _Pragma("unroll")                                                  \
            for (int j = 0; j < 16; ++j) {                                     \
                const unsigned bit = 1u << ((j & 3) + 8 * (j >> 2));           \
                float p0 = EXP2(s[0][j] - m2); p0 = (mw0 & bit) ? 0.0f : p0;   \
                float p1 = EXP2(s[1][j] - m2); p1 = (mw1 & bit) ? 0.0f : p1;   \
                float p2 = EXP2(s[2][j] - m2); p2 = (mw2 & bit) ? 0.0f : p2;   \
                float p3 = EXP2(s[3][j] - m2); p3 = (mw3 & bit) ? 0.0f : p3;   \
                s[0][j] = p0; s[1][j] = p1; s[2][j] = p2; s[3][j] = p3;        \
                rs += (p0 + p1) + (p2 + p3);                                   \
            }                                                                  \
        }                                                                      \
        rs += __shfl_xor(rs, 32);                                              \
        l_i += rs;                                                             \
        __builtin_amdgcn_s_setprio(1);                                         \
        _Pragma("unroll")                                                      \
        for (int c = 0; c < 8; ++c) {                                          \
            const int ko = c >> 1, cc = c & 1;                                 \
            bf16x8 pb;                                                         \
            _Pragma("unroll")                                                  \
            for (int r = 0; r < 8; ++r) pb[r] = (__bf16)s[ko][cc * 8 + r];     \
            _Pragma("unroll")                                                  \
            for (int dd = 0; dd < 4; ++dd) {                                   \
                bf16x8 va = *(const bf16x8*)(vp[c] + (BUF) * 16384 + dd * 4096); \
                o[dd] = __builtin_amdgcn_mfma_f32_32x32x16_bf16(va, pb, o[dd], 0, 0, 0); \
            }                                                                  \
        }                                                                      \
        __builtin_amdgcn_s_setprio(0);                                         \
    } while (0)

#define HALF_ITER(BUF, MREG)                                                   \
    do {                                                                       \
        COMPUTE_TILE(BUF, MREG);                                               \
        BAR();                                                                 \
        ISSUE_LDS(BUF);                                                        \
        ISSUE_M(MREG);                                                         \
        WAIT_VM(9);                                                            \
        BAR();                                                                 \
    } while (0)

__global__ __launch_bounds__(512, 2)
void attn_fwd(const float* __restrict__ Q, const __bf16* __restrict__ Kimg,
              const __bf16* __restrict__ Vimg, const unsigned* __restrict__ MB,
              float* __restrict__ O)
{
    // flat LDS: [K buf0 | K buf1 | V buf0 | V buf1] = 128 KB
    __shared__ __bf16 SM[4 * TILE_ELEMS];

    const int tid  = threadIdx.x;
    const int lane = tid & 63;
    const int ln31 = lane & 31;
    const int h    = lane >> 5;
    const int sw   = lane & 7;        // XOR key = row&7 (row = lane&31)
    const int w    = tid >> 6;        // wave 0..7
    const int sh4  = 4 * h;

    // bijective XCD-chunked swizzle: nwg=256, 8 XCDs, 32 blocks/XCD
    const int bid = blockIdx.x;
    const int swz = (bid & 7) * 32 + (bid >> 3);
    const int qb  = swz & 7;          // 8 q-blocks per bh
    const int bh  = swz >> 3;
    const int b   = bh >> 4;

    const float SC = 0.08838834764831845f * 1.4426950408889634f; // /sqrt(d)*log2e

    const float* Qb = Q + (size_t)bh * SS * DD;
    float*       Ob = O + (size_t)bh * SS * DD;

    const int qrow = qb * QBLK + w * 32 + ln31;

    // running global pointers
    const __bf16*   kgp = Kimg + (size_t)bh * 16 * TILE_ELEMS + w * 2048 + lane * 8;
    const __bf16*   vgp = Vimg + (size_t)bh * 16 * TILE_ELEMS + w * 2048 + lane * 8;
    const unsigned* mp  = MB + ((size_t)b * 2048 + qrow) * 64;

    // precomputed LDS lane bases: unit (j*2+h)^sw within row ln31
    const __bf16* kp[8];
    const __bf16* vp[8];
    #pragma unroll
    for (int j = 0; j < 8; ++j) {
        const int u = ((j * 2 + h) ^ sw) * 8;
        kp[j] = SM + ln31 * 128 + u;
        vp[j] = SM + 32768 + ln31 * 128 + u;
    }

    // ---- Q fragment (B-operand), pre-scaled, slot (h,r) = d0*16 + 8h + r ----
    bf16x8 qf[8];
    {
        const float* qr = Qb + (size_t)qrow * DD + 8 * h;
        #pragma unroll
        for (int d0 = 0; d0 < 8; ++d0) {
            float4 f0 = *(const float4*)(qr + d0 * 16);
            float4 f1 = *(const float4*)(qr + d0 * 16 + 4);
            bf16x8 a;
            a[0]=(__bf16)(f0.x*SC); a[1]=(__bf16)(f0.y*SC);
            a[2]=(__bf16)(f0.z*SC); a[3]=(__bf16)(f0.w*SC);
            a[4]=(__bf16)(f1.x*SC); a[5]=(__bf16)(f1.y*SC);
            a[6]=(__bf16)(f1.z*SC); a[7]=(__bf16)(f1.w*SC);
            qf[d0] = a;
        }
    }
    __builtin_amdgcn_sched_barrier(0);

    f32x16 o[4];
    #pragma unroll
    for (int i = 0; i < 4; ++i) o[i] = (f32x16)0.0f;
    float m2 = -1e30f, l_i = 0.0f;

    int4 mA, mB2;

    // ---- prologue: 2 tiles in flight (9 VMEM ops each) ----
    ISSUE_LDS(0);
    ISSUE_M(mA);
    ISSUE_LDS(1);
    ISSUE_M(mB2);
    WAIT_VM(9);
    BAR();

    // ---- main loop: counted vmcnt, never drained to 0 ----
    #pragma unroll 1
    for (int t = 0; t + 3 < NT; t += 2) {
        HALF_ITER(0, mA);
        HALF_ITER(1, mB2);
    }
    // tail: tiles NT-2, NT-1
    COMPUTE_TILE(0, mA);
    WAIT_VM(0);
    BAR();
    COMPUTE_TILE(1, mB2);

    // ---- epilogue: lane owns q=qrow; d = dd*32 + 8*rg + 4h + j ----
    const float inv = 1.0f / l_i;
    float* orow = Ob + (size_t)qrow * DD + 4 * h;
    #pragma unroll
    for (int dd = 0; dd < 4; ++dd) {
        #pragma unroll
        for (int rg = 0; rg < 4; ++rg) {
            float4 st;
            st.x = o[dd][rg*4+0] * inv; st.y = o[dd][rg*4+1] * inv;
            st.z = o[dd][rg*4+2] * inv; st.w = o[dd][rg*4+3] * inv;
            *(float4*)&orow[dd * 32 + rg * 8] = st;
        }
    }
}

extern "C" void kernel_launch(void* const* d_in, const int* in_sizes, int n_in,
                              void* d_out, int out_size, void* d_ws, size_t ws_size,
                              hipStream_t stream) {
    const float* Q = (const float*)d_in[0];
    const float* K = (const float*)d_in[1];
    const float* V = (const float*)d_in[2];
    const int*   M = (const int*)d_in[4];
    float*       O = (float*)d_out;

    __bf16*   Kimg = (__bf16*)d_ws;                         // 16.78 MB
    __bf16*   Vimg = Kimg + (size_t)BB * HH * SS * DD;      // 16.78 MB
    unsigned* Mbit = (unsigned*)(Vimg + (size_t)BB * HH * SS * DD);  // 1 MB

    kimg_prep<<<1024, 256, 0, stream>>>(K, Kimg);
    vimg_prep<<<4096, 256, 0, stream>>>(V, Vimg);
    mprep    <<<32768, 256, 0, stream>>>(M, Mbit);

    attn_fwd<<<BB * HH * (SS / QBLK), 512, 0, stream>>>(Q, Kimg, Vimg, Mbit, O);
}

// Round 10
// 131.923 us; speedup vs baseline: 2.6814x; 1.0226x over previous
//
#include <hip/hip_runtime.h>
#include <hip/hip_bf16.h>

#define BB 2
#define HH 16
#define SS 2048
#define DD 128
#define QBLK 128
#define KVBLK 64
#define NT (SS / KVBLK)            // 32
#define TILE_ELEMS (KVBLK * DD)    // 8192 bf16 = 16 KB per K or V tile

typedef __bf16 bf16x8 __attribute__((ext_vector_type(8)));
typedef float  f32x16 __attribute__((ext_vector_type(16)));

#define EXP2(x) __builtin_amdgcn_exp2f(x)

// ============ pre-pass 1: K fp32 -> bf16 flat image (16B-unit XOR swizzle) ============
// unit g: row = g>>4, stored unit u' = g&15 holds K[row][(u'^(row&7))*8 ..+8]
// total units = BB*HH*SS*DD/8 = 1,048,576  ->  grid 1024 x 256 x 4 units
__global__ __launch_bounds__(256)
void kimg_prep(const float* __restrict__ K, __bf16* __restrict__ Kd)
{
    #pragma unroll
    for (int i = 0; i < 4; ++i) {
        const int g   = blockIdx.x * 1024 + i * 256 + threadIdx.x;
        const int row = g >> 4;
        const int u   = (g & 15) ^ (row & 7);
        const float* src = K + (size_t)row * 128 + u * 8;
        float4 f0 = *(const float4*)src;
        float4 f1 = *(const float4*)(src + 4);
        bf16x8 h;
        h[0]=(__bf16)f0.x; h[1]=(__bf16)f0.y; h[2]=(__bf16)f0.z; h[3]=(__bf16)f0.w;
        h[4]=(__bf16)f1.x; h[5]=(__bf16)f1.y; h[6]=(__bf16)f1.z; h[7]=(__bf16)f1.w;
        *(bf16x8*)(Kd + (size_t)g * 8) = h;
    }
}

// ===== pre-pass 2: V -> V^T tile image (KVBLK=64); unit (d,iu): us=iu^(d&7),
// c=us>>1, hh=us&1; elem j = V[tile*64 + c*16 + 4hh + (j&3)+8*(j>>2)][d]
// total units = 1,048,576 -> grid 4096 x 256, 1 unit/thread
__global__ __launch_bounds__(256)
void vimg_prep(const float* __restrict__ V, __bf16* __restrict__ Vd)
{
    const int g    = blockIdx.x * 256 + threadIdx.x;
    const int tile = g >> 10;                 // 0..1023
    const int wu   = g & 1023;
    const int d    = wu >> 3;
    const int iu   = wu & 7;
    const int us   = iu ^ (d & 7);
    const int c    = us >> 1;
    const int hh   = us & 1;
    const float* src = V + ((size_t)tile * 64 + c * 16 + 4 * hh) * 128 + d;
    bf16x8 o;
    #pragma unroll
    for (int j = 0; j < 8; ++j) {
        const int roff = (j & 3) + 8 * (j >> 2);
        o[j] = (__bf16)src[(size_t)roff * 128];
    }
    *(bf16x8*)(Vd + (size_t)g * 8) = o;
}

// ============ pre-pass 3: mask int32 -> bit-packed words (ballot) ============
__global__ __launch_bounds__(256)
void mprep(const int* __restrict__ M, unsigned* __restrict__ mb)
{
    const int wid  = blockIdx.x * 4 + (threadIdx.x >> 6);  // 131072 waves
    const int lane = threadIdx.x & 63;
    const int kb   = wid & 31;
    const int q    = (wid >> 5) & 2047;
    const int b    = wid >> 16;
    const int mi   = M[((size_t)b * 2048 + q) * 2048 + kb * 64 + lane];
    const unsigned long long bal = __ballot(mi != 0);
    if (lane == 0) {
        uint2 st; st.x = (unsigned)bal; st.y = (unsigned)(bal >> 32);
        *(uint2*)&mb[((size_t)b * 2048 + q) * 64 + kb * 2] = st;
    }
}

// ============================== main attention kernel ==============================
__device__ __forceinline__ void load_lds16(const __bf16* g, __bf16* l) {
    __builtin_amdgcn_global_load_lds(
        (const __attribute__((address_space(1))) void*)g,
        (__attribute__((address_space(3))) void*)l, 16, 0, 0);
}

#define WAIT_VM(N)                                                             \
    do {                                                                       \
        asm volatile("s_waitcnt vmcnt(" #N ")" ::: "memory");                  \
        __builtin_amdgcn_sched_barrier(0);                                     \
    } while (0)

#define BAR() __builtin_amdgcn_s_barrier()

// 8 glds issues per wave (4 K + 4 V) + advance
#define ISSUE_LDS(BUF)                                                         \
    do {                                                                       \
        _Pragma("unroll")                                                      \
        for (int i = 0; i < 4; ++i)                                            \
            load_lds16(kgp + i * 512, SM + (BUF) * 8192 + w * 2048 + i * 512); \
        _Pragma("unroll")                                                      \
        for (int i = 0; i < 4; ++i)                                            \
            load_lds16(vgp + i * 512, SM + 16384 + (BUF) * 8192 + w * 2048 + i * 512); \
        kgp += TILE_ELEMS;                                                     \
        vgp += TILE_ELEMS;                                                     \
    } while (0)

#define ISSUE_M(MST)                                                           \
    do { MST = *(const uint2*)mp; mp += 2; } while (0)

#define COMPUTE_TILE(BUF, MST)                                                 \
    do {                                                                       \
        f32x16 s[2];                                                           \
        __builtin_amdgcn_s_setprio(1);                                         \
        _Pragma("unroll")                                                      \
        for (int ko = 0; ko < 2; ++ko) {                                       \
            s[ko] = (f32x16)0.0f;                                              \
            _Pragma("unroll")                                                  \
            for (int d0 = 0; d0 < 8; ++d0) {                                   \
                bf16x8 kf = *(const bf16x8*)(kp[d0] + (BUF) * 8192 + ko * 4096); \
                s[ko] = __builtin_amdgcn_mfma_f32_32x32x16_bf16(kf, qf[d0], s[ko], 0, 0, 0); \
            }                                                                  \
        }                                                                      \
        __builtin_amdgcn_s_setprio(0);                                         \
        float mx = s[0][0];                                                    \
        _Pragma("unroll")                                                      \
        for (int ko = 0; ko < 2; ++ko)                                         \
            _Pragma("unroll")                                                  \
            for (int j = (ko ? 0 : 1); j < 16; ++j) mx = fmaxf(mx, s[ko][j]);  \
        mx = fmaxf(mx, __shfl_xor(mx, 32));                                    \
        if (__any(mx > m2 + 11.5415603f)) {   /* defer-max: rarely taken */    \
            const float newm  = fmaxf(m2, mx);                                 \
            const float alpha = EXP2(m2 - newm);                               \
            m2 = newm;                                                         \
            l_i *= alpha;                                                      \
            _Pragma("unroll")                                                  \
            for (int dd = 0; dd < 4; ++dd)                                     \
                _Pragma("unroll")                                              \
                for (int j = 0; j < 16; ++j) o[dd][j] *= alpha;                \
        }                                                                      \
        float rs = 0.0f;                                                       \
        {                                                                      \
            const unsigned mw0 = (MST.x) >> sh4;                               \
            const unsigned mw1 = (MST.y) >> sh4;                               \
            _Pragma("unroll")                                                  \
            for (int j = 0; j < 16; ++j) {                                     \
                const unsigned bit = 1u << ((j & 3) + 8 * (j >> 2));           \
                float p0 = EXP2(s[0][j] - m2); p0 = (mw0 & bit) ? 0.0f : p0;   \
                float p1 = EXP2(s[1][j] - m2); p1 = (mw1 & bit) ? 0.0f : p1;   \
                s[0][j] = p0; s[1][j] = p1;                                    \
                rs += p0 + p1;                                                 \
            }                                                                  \
        }                                                                      \
        rs += __shfl_xor(rs, 32);                                              \
        l_i += rs;                                                             \
        __builtin_amdgcn_s_setprio(1);                                         \
        _Pragma("unroll")                                                      \
        for (int c = 0; c < 4; ++c) {                                          \
            const int ko = c >> 1, cc = c & 1;                                 \
            bf16x8 pb;                                                         \
            _Pragma("unroll")                                                  \
            for (int r = 0; r < 8; ++r) pb[r] = (__bf16)s[ko][cc * 8 + r];     \
            _Pragma("unroll")                                                  \
            for (int dd = 0; dd < 4; ++dd) {                                   \
                bf16x8 va = *(const bf16x8*)(vp[c] + (BUF) * 8192 + dd * 2048); \
                o[dd] = __builtin_amdgcn_mfma_f32_32x32x16_bf16(va, pb, o[dd], 0, 0, 0); \
            }                                                                  \
        }                                                                      \
        __builtin_amdgcn_s_setprio(0);                                         \
    } while (0)

#define HALF_ITER(BUF, MREG)                                                   \
    do {                                                                       \
        COMPUTE_TILE(BUF, MREG);                                               \
        BAR();                                                                 \
        ISSUE_LDS(BUF);                                                        \
        ISSUE_M(MREG);                                                         \
        WAIT_VM(9);                                                            \
        BAR();                                                                 \
    } while (0)

__global__ __launch_bounds__(256, 2)
void attn_fwd(const float* __restrict__ Q, const __bf16* __restrict__ Kimg,
              const __bf16* __restrict__ Vimg, const unsigned* __restrict__ MB,
              float* __restrict__ O)
{
    // flat LDS: [K buf0 | K buf1 | V buf0 | V buf1] = 64 KB -> 2 blocks/CU
    __shared__ __bf16 SM[4 * TILE_ELEMS];

    const int tid  = threadIdx.x;
    const int lane = tid & 63;
    const int ln31 = lane & 31;
    const int h    = lane >> 5;
    const int sw   = lane & 7;        // XOR key = row&7 (row = lane&31)
    const int w    = tid >> 6;        // wave 0..3
    const int sh4  = 4 * h;

    // bijective XCD-chunked swizzle: nwg=512, 8 XCDs, 64 blocks/XCD
    const int bid = blockIdx.x;
    const int swz = (bid & 7) * 64 + (bid >> 3);
    const int qb  = swz & 15;         // 16 q-blocks per bh
    const int bh  = swz >> 4;
    const int b   = bh >> 4;

    const float SC = 0.08838834764831845f * 1.4426950408889634f; // /sqrt(d)*log2e

    const float* Qb = Q + (size_t)bh * SS * DD;
    float*       Ob = O + (size_t)bh * SS * DD;

    const int qrow = qb * QBLK + w * 32 + ln31;

    // running global pointers
    const __bf16*   kgp = Kimg + (size_t)bh * SS * DD + w * 2048 + lane * 8;
    const __bf16*   vgp = Vimg + (size_t)bh * SS * DD + w * 2048 + lane * 8;
    const unsigned* mp  = MB + ((size_t)b * 2048 + qrow) * 64;

    // precomputed LDS lane bases: unit (2j+h)^sw within row ln31
    const __bf16* kp[8];
    const __bf16* vp[4];
    #pragma unroll
    for (int j = 0; j < 8; ++j)
        kp[j] = SM + ln31 * 128 + (((j * 2 + h) ^ sw) * 8);
    #pragma unroll
    for (int j = 0; j < 4; ++j)
        vp[j] = SM + 16384 + ln31 * 64 + (((j * 2 + h) ^ sw) * 8);

    // ---- Q fragment (B-operand), pre-scaled, slot (h,r) = d0*16 + 8h + r ----
    bf16x8 qf[8];
    {
        const float* qr = Qb + (size_t)qrow * DD + 8 * h;
        #pragma unroll
        for (int d0 = 0; d0 < 8; ++d0) {
            float4 f0 = *(const float4*)(qr + d0 * 16);
            float4 f1 = *(const float4*)(qr + d0 * 16 + 4);
            bf16x8 a;
            a[0]=(__bf16)(f0.x*SC); a[1]=(__bf16)(f0.y*SC);
            a[2]=(__bf16)(f0.z*SC); a[3]=(__bf16)(f0.w*SC);
            a[4]=(__bf16)(f1.x*SC); a[5]=(__bf16)(f1.y*SC);
            a[6]=(__bf16)(f1.z*SC); a[7]=(__bf16)(f1.w*SC);
            qf[d0] = a;
        }
    }
    __builtin_amdgcn_sched_barrier(0);

    f32x16 o[4];
    #pragma unroll
    for (int i = 0; i < 4; ++i) o[i] = (f32x16)0.0f;
    float m2 = -1e30f, l_i = 0.0f;

    uint2 mA, mB2;

    // ---- prologue: 2 tiles in flight (9 VMEM ops each) ----
    ISSUE_LDS(0);
    ISSUE_M(mA);
    ISSUE_LDS(1);
    ISSUE_M(mB2);
    WAIT_VM(9);
    BAR();

    // ---- main loop: counted vmcnt, never drained to 0 ----
    #pragma unroll 1
    for (int t = 0; t + 3 < NT; t += 2) {
        HALF_ITER(0, mA);
        HALF_ITER(1, mB2);
    }
    // tail: tiles NT-2, NT-1
    COMPUTE_TILE(0, mA);
    WAIT_VM(0);
    BAR();
    COMPUTE_TILE(1, mB2);

    // ---- epilogue: lane owns q=qrow; d = dd*32 + rg*8 + 4h + j ----
    const float inv = 1.0f / l_i;
    float* orow = Ob + (size_t)qrow * DD + 4 * h;
    #pragma unroll
    for (int dd = 0; dd < 4; ++dd) {
        #pragma unroll
        for (int rg = 0; rg < 4; ++rg) {
            float4 st;
            st.x = o[dd][rg*4+0] * inv; st.y = o[dd][rg*4+1] * inv;
            st.z = o[dd][rg*4+2] * inv; st.w = o[dd][rg*4+3] * inv;
            *(float4*)&orow[dd * 32 + rg * 8] = st;
        }
    }
}

extern "C" void kernel_launch(void* const* d_in, const int* in_sizes, int n_in,
                              void* d_out, int out_size, void* d_ws, size_t ws_size,
                              hipStream_t stream) {
    const float* Q = (const float*)d_in[0];
    const float* K = (const float*)d_in[1];
    const float* V = (const float*)d_in[2];
    const int*   M = (const int*)d_in[4];
    float*       O = (float*)d_out;

    __bf16*   Kimg = (__bf16*)d_ws;                         // 16.78 MB
    __bf16*   Vimg = Kimg + (size_t)BB * HH * SS * DD;      // 16.78 MB
    unsigned* Mbit = (unsigned*)(Vimg + (size_t)BB * HH * SS * DD);  // 1 MB

    kimg_prep<<<1024, 256, 0, stream>>>(K, Kimg);    // 1,048,576 units
    vimg_prep<<<4096, 256, 0, stream>>>(V, Vimg);    // 1,048,576 units
    mprep    <<<32768, 256, 0, stream>>>(M, Mbit);

    attn_fwd<<<BB * HH * (SS / QBLK), 256, 0, stream>>>(Q, Kimg, Vimg, Mbit, O);
}